// Round 2
// baseline (790.426 us; speedup 1.0000x reference)
//
#include <hip/hip_runtime.h>
#include <hip/hip_bf16.h>

#define D 128

typedef __attribute__((ext_vector_type(8))) short short8;
typedef __attribute__((ext_vector_type(4))) float float4v;

__device__ __forceinline__ float4v mfma16(short8 a, short8 b, float4v c) {
  return __builtin_amdgcn_mfma_f32_16x16x32_bf16(a, b, c, 0, 0, 0);
}
__device__ __forceinline__ float b2f(__hip_bfloat16 x) { return __bfloat162float(x); }
__device__ __forceinline__ __hip_bfloat16 f2b(float x) { return __float2bfloat16(x); }

__device__ __forceinline__ float ldf(const float* p, size_t i) { return p[i]; }
__device__ __forceinline__ float ldf(const __hip_bfloat16* p, size_t i) { return b2f(p[i]); }
__device__ __forceinline__ void stf(float* p, size_t i, float v) { p[i] = v; }
__device__ __forceinline__ void stf(__hip_bfloat16* p, size_t i, float v) { p[i] = f2b(v); }

// ---------------- fp32 -> bf16 casts ----------------
__global__ void k_cast(const float* __restrict__ in, __hip_bfloat16* __restrict__ out,
                       int n4) {
  int i = blockIdx.x * 256 + threadIdx.x;
  if (i < n4) {
    float4 v = ((const float4*)in)[i];
    __hip_bfloat16 o[4] = {f2b(v.x), f2b(v.y), f2b(v.z), f2b(v.w)};
    ((short4*)out)[i] = *(short4*)o;
  }
}

__global__ void k_cast_w(const float* __restrict__ wq, const float* __restrict__ wk,
                         const float* __restrict__ wv, const float* __restrict__ wo,
                         const float* __restrict__ w1, const float* __restrict__ w2,
                         __hip_bfloat16* __restrict__ oq, __hip_bfloat16* __restrict__ ok,
                         __hip_bfloat16* __restrict__ ov, __hip_bfloat16* __restrict__ oo,
                         __hip_bfloat16* __restrict__ o1, __hip_bfloat16* __restrict__ o2) {
  int i = blockIdx.x * 256 + threadIdx.x;  // 131072 total
  if (i < 16384) oq[i] = f2b(wq[i]);
  else if (i < 32768) ok[i - 16384] = f2b(wk[i - 16384]);
  else if (i < 49152) ov[i - 32768] = f2b(wv[i - 32768]);
  else if (i < 65536) oo[i - 49152] = f2b(wo[i - 49152]);
  else if (i < 98304) o1[i - 65536] = f2b(w1[i - 65536]);
  else o2[i - 98304] = f2b(w2[i - 98304]);
}

// ---------------- CSR build ----------------
__global__ void k_hist(const int* __restrict__ dst, int* __restrict__ deg, int E) {
  int e = blockIdx.x * 256 + threadIdx.x;
  if (e < E) atomicAdd(&deg[dst[e]], 1);
}

__global__ void k_scan1(const int* __restrict__ deg, int* __restrict__ offs,
                        int* __restrict__ bsum, int N) {
  __shared__ int sd[256];
  int b = blockIdx.x, t = threadIdx.x;
  int base = b * 1024 + t * 4;
  int v0 = 0, v1 = 0, v2 = 0, v3 = 0;
  if (base + 0 < N) v0 = deg[base + 0];
  if (base + 1 < N) v1 = deg[base + 1];
  if (base + 2 < N) v2 = deg[base + 2];
  if (base + 3 < N) v3 = deg[base + 3];
  int s = v0 + v1 + v2 + v3;
  sd[t] = s;
  __syncthreads();
  for (int ofs = 1; ofs < 256; ofs <<= 1) {
    int x = (t >= ofs) ? sd[t - ofs] : 0;
    __syncthreads();
    sd[t] += x;
    __syncthreads();
  }
  int run = sd[t] - s;  // exclusive prefix for this thread
  if (base + 0 < N) offs[base + 0] = run; run += v0;
  if (base + 1 < N) offs[base + 1] = run; run += v1;
  if (base + 2 < N) offs[base + 2] = run; run += v2;
  if (base + 3 < N) offs[base + 3] = run;
  if (t == 255) bsum[b] = sd[255];
}

__global__ void k_scan2(int* __restrict__ bsum, int B) {
  __shared__ int sd[256];
  int t = threadIdx.x;
  int v = (t < B) ? bsum[t] : 0;
  sd[t] = v;
  __syncthreads();
  for (int ofs = 1; ofs < 256; ofs <<= 1) {
    int x = (t >= ofs) ? sd[t - ofs] : 0;
    __syncthreads();
    sd[t] += x;
    __syncthreads();
  }
  if (t < B) bsum[t] = sd[t] - v;  // exclusive
}

__global__ void k_scan3(int* __restrict__ offs, int* __restrict__ cur,
                        const int* __restrict__ bsum, int N) {
  int b = blockIdx.x, t = threadIdx.x;
  int add = bsum[b];
  int base = b * 1024 + t * 4;
#pragma unroll
  for (int j = 0; j < 4; ++j) {
    int i = base + j;
    if (i < N) { int o = offs[i] + add; offs[i] = o; cur[i] = o; }
  }
}

__global__ void k_fill(const int* __restrict__ src, const int* __restrict__ dst,
                       int* __restrict__ cur, int* __restrict__ csr, int E) {
  int e = blockIdx.x * 256 + threadIdx.x;
  if (e < E) {
    int p = atomicAdd(&cur[dst[e]], 1);
    csr[p] = src[e];
  }
}

// ---------------- GEMM (per-wave 16x16 tile, B frags in regs) ----------------
template <int K, bool RELU>
__global__ __launch_bounds__(64) void gemm_plain(const short* __restrict__ A,
                                                 const short* __restrict__ B,
                                                 const float* __restrict__ bias,
                                                 __hip_bfloat16* __restrict__ Out,
                                                 int Nrow, int M) {
  const int lane = threadIdx.x & 63;
  const int ct = blockIdx.y;
  const int n = lane & 15, quad = lane >> 4;
  short8 bfr[K / 32];
#pragma unroll
  for (int c = 0; c < K / 32; ++c) {
    short8 tmp;
#pragma unroll
    for (int j = 0; j < 8; ++j)
      tmp[j] = B[(size_t)(c * 32 + quad * 8 + j) * M + ct * 16 + n];
    bfr[c] = tmp;
  }
  float biasv = bias ? bias[ct * 16 + n] : 0.f;
  int ntiles = Nrow >> 4;
  for (int rt = blockIdx.x; rt < ntiles; rt += gridDim.x) {
    float4v acc = {0.f, 0.f, 0.f, 0.f};
    const short* Ap = A + (size_t)(rt * 16 + n) * K + quad * 8;
#pragma unroll
    for (int c = 0; c < K / 32; ++c)
      acc = mfma16(*(const short8*)(Ap + c * 32), bfr[c], acc);
#pragma unroll
    for (int r = 0; r < 4; ++r) {
      int grow = rt * 16 + quad * 4 + r;
      float v = acc[r] + biasv;
      if (RELU) v = fmaxf(v, 0.f);
      Out[(size_t)grow * M + ct * 16 + n] = f2b(v);
    }
  }
}

// ------ GEMM + bias + residual + LayerNorm (M=128 fixed), fp32/bf16 generic ------
template <int K, typename TR, typename TO>
__global__ __launch_bounds__(512) void ln_gemm(const short* __restrict__ A,
                                               const short* __restrict__ B,
                                               const float* __restrict__ bias,
                                               const TR* __restrict__ resid,
                                               const float* __restrict__ gam,
                                               const float* __restrict__ bet,
                                               TO* __restrict__ Out, int Nrow) {
  __shared__ float tile[16][132];
  const int t = threadIdx.x;
  const int lane = t & 63;
  const int ct = t >> 6;  // wave id = col tile (8 waves x 16 cols = 128)
  const int n = lane & 15, quad = lane >> 4;
  short8 bfr[K / 32];
#pragma unroll
  for (int c = 0; c < K / 32; ++c) {
    short8 tmp;
#pragma unroll
    for (int j = 0; j < 8; ++j)
      tmp[j] = B[(size_t)(c * 32 + quad * 8 + j) * 128 + ct * 16 + n];
    bfr[c] = tmp;
  }
  float biasv = bias[ct * 16 + n];
  const int row2 = t >> 5, sub = t & 31;
  float ga0 = gam[sub],      ga1 = gam[sub + 32];
  float ga2 = gam[sub + 64], ga3 = gam[sub + 96];
  float be0 = bet[sub],      be1 = bet[sub + 32];
  float be2 = bet[sub + 64], be3 = bet[sub + 96];
  int ntiles = Nrow >> 4;
  for (int rt = blockIdx.x; rt < ntiles; rt += gridDim.x) {
    float4v acc = {0.f, 0.f, 0.f, 0.f};
    const short* Ap = A + (size_t)(rt * 16 + n) * K + quad * 8;
#pragma unroll
    for (int c = 0; c < K / 32; ++c)
      acc = mfma16(*(const short8*)(Ap + c * 32), bfr[c], acc);
#pragma unroll
    for (int r = 0; r < 4; ++r) {
      int rr = quad * 4 + r;
      size_t g = (size_t)(rt * 16 + rr) * 128 + ct * 16 + n;
      tile[rr][ct * 16 + n] = acc[r] + biasv + ldf(resid, g);
    }
    __syncthreads();
    float x0 = tile[row2][sub], x1 = tile[row2][sub + 32];
    float x2 = tile[row2][sub + 64], x3 = tile[row2][sub + 96];
    float s = x0 + x1 + x2 + x3;
    float s2 = x0 * x0 + x1 * x1 + x2 * x2 + x3 * x3;
#pragma unroll
    for (int o = 16; o >= 1; o >>= 1) {
      s += __shfl_xor(s, o);
      s2 += __shfl_xor(s2, o);
    }
    float mean = s * 0.0078125f;
    float var = s2 * 0.0078125f - mean * mean;
    float rstd = rsqrtf(var + 1e-5f);
    size_t base = (size_t)(rt * 16 + row2) * 128;
    stf(Out, base + sub,      (x0 - mean) * rstd * ga0 + be0);
    stf(Out, base + sub + 32, (x1 - mean) * rstd * ga1 + be1);
    stf(Out, base + sub + 64, (x2 - mean) * rstd * ga2 + be2);
    stf(Out, base + sub + 96, (x3 - mean) * rstd * ga3 + be3);
    __syncthreads();
  }
}

// ---------------- dst-centric attention aggregation ----------------
__global__ __launch_bounds__(128) void attn_agg(const __hip_bfloat16* __restrict__ Q,
                                                const __hip_bfloat16* __restrict__ Kb,
                                                const __hip_bfloat16* __restrict__ V,
                                                const int* __restrict__ offs,
                                                const int* __restrict__ deg,
                                                const int* __restrict__ csr,
                                                __hip_bfloat16* __restrict__ AT) {
  const int node = blockIdx.x;
  const int t = threadIdx.x;  // 0..127 : head = t>>4, dim = t&15
  const float q = b2f(Q[(size_t)node * 128 + t]);
  const int start = offs[node];
  const int dg = deg[node];
  float z = 0.f, acc = 0.f;
  for (int i = 0; i < dg; ++i) {
    int s = csr[start + i];
    float k = b2f(Kb[(size_t)s * 128 + t]);
    float p = q * k;
    p += __shfl_xor(p, 1);
    p += __shfl_xor(p, 2);
    p += __shfl_xor(p, 4);
    p += __shfl_xor(p, 8);
    float sc = __expf(fminf(fmaxf(p * 0.25f, -5.f), 5.f));
    float v = b2f(V[(size_t)s * 128 + t]);
    acc = fmaf(sc, v, acc);
    z += sc;
  }
  float o = (z > 0.f) ? acc / z : acc;
  AT[(size_t)node * 128 + t] = f2b(o);
}

// ---------------- launch ----------------
extern "C" void kernel_launch(void* const* d_in, const int* in_sizes, int n_in,
                              void* d_out, int out_size, void* d_ws, size_t ws_size,
                              hipStream_t stream) {
  const float* h = (const float*)d_in[0];
  const int* src = (const int*)d_in[1];
  const int* dst = (const int*)d_in[2];
  const float* Wq = (const float*)d_in[3];
  const float* Wk = (const float*)d_in[4];
  const float* Wv = (const float*)d_in[5];
  const float* Wo = (const float*)d_in[6];
  const float* bo = (const float*)d_in[7];
  const float* g1 = (const float*)d_in[8];
  const float* b1 = (const float*)d_in[9];
  const float* g2 = (const float*)d_in[10];
  const float* b2 = (const float*)d_in[11];
  const float* W1 = (const float*)d_in[12];
  const float* c1 = (const float*)d_in[13];
  const float* W2 = (const float*)d_in[14];
  const float* c2 = (const float*)d_in[15];

  const int N = in_sizes[0] / D;
  const int E = in_sizes[1];

  char* p = (char*)d_ws;
  auto carve = [&](size_t bytes) {
    char* r = p;
    p += (bytes + 255) & ~(size_t)255;
    return r;
  };
  short* hb = (short*)carve((size_t)N * D * 2);   // bf16 h; later reused as AT
  short* Qb = (short*)carve((size_t)N * D * 2);
  short* Kb = (short*)carve((size_t)N * D * 2);   // contiguous with Vb
  short* Vb = (short*)carve((size_t)N * D * 2);
  short* wq = (short*)carve(16384 * 2);
  short* wk = (short*)carve(16384 * 2);
  short* wv = (short*)carve(16384 * 2);
  short* wo = (short*)carve(16384 * 2);
  short* w1 = (short*)carve(32768 * 2);
  short* w2 = (short*)carve(32768 * 2);
  int* deg = (int*)carve((size_t)N * 4);
  int* offs = (int*)carve((size_t)N * 4);
  int* cur = (int*)carve((size_t)N * 4);
  int* bsum = (int*)carve(1024);
  int* csr = (int*)carve((size_t)E * 4);
  short* ATb = hb;   // alias: h-bf16 dead after QKV gemms
  short* hh = Qb;    // alias: Q dead after attn_agg
  short* tmid = Kb;  // alias: spans Kb+Vb (N*256 bf16), K/V dead after attn_agg

  hipMemsetAsync(deg, 0, (size_t)N * 4, stream);
  int eb = (E + 255) / 256;
  k_hist<<<eb, 256, 0, stream>>>(dst, deg, E);
  int B1 = (N + 1023) / 1024;
  k_scan1<<<B1, 256, 0, stream>>>(deg, offs, bsum, N);
  k_scan2<<<1, 256, 0, stream>>>(bsum, B1);
  k_scan3<<<B1, 256, 0, stream>>>(offs, cur, bsum, N);
  k_fill<<<eb, 256, 0, stream>>>(src, dst, cur, csr, E);

  int n4 = N * D / 4;
  k_cast<<<(n4 + 255) / 256, 256, 0, stream>>>(h, (__hip_bfloat16*)hb, n4);
  k_cast_w<<<512, 256, 0, stream>>>(Wq, Wk, Wv, Wo, W1, W2,
                                    (__hip_bfloat16*)wq, (__hip_bfloat16*)wk,
                                    (__hip_bfloat16*)wv, (__hip_bfloat16*)wo,
                                    (__hip_bfloat16*)w1, (__hip_bfloat16*)w2);

  dim3 g8(1024, 8), g16(1024, 16);
  gemm_plain<128, false><<<g8, 64, 0, stream>>>(hb, wq, nullptr,
                                                (__hip_bfloat16*)Qb, N, 128);
  gemm_plain<128, false><<<g8, 64, 0, stream>>>(hb, wk, nullptr,
                                                (__hip_bfloat16*)Kb, N, 128);
  gemm_plain<128, false><<<g8, 64, 0, stream>>>(hb, wv, nullptr,
                                                (__hip_bfloat16*)Vb, N, 128);

  attn_agg<<<N, 128, 0, stream>>>((const __hip_bfloat16*)Qb, (const __hip_bfloat16*)Kb,
                                  (const __hip_bfloat16*)Vb, offs, deg, csr,
                                  (__hip_bfloat16*)ATb);

  ln_gemm<128, float, __hip_bfloat16><<<1024, 512, 0, stream>>>(
      ATb, wo, bo, h, g1, b1, (__hip_bfloat16*)hh, N);
  gemm_plain<128, true><<<g16, 64, 0, stream>>>(hh, w1, c1, (__hip_bfloat16*)tmid, N, 256);
  ln_gemm<256, __hip_bfloat16, float><<<1024, 512, 0, stream>>>(
      tmid, w2, c2, (const __hip_bfloat16*)hh, g2, b2, (float*)d_out, N);
}

// Round 3
// 615.334 us; speedup vs baseline: 1.2845x; 1.2845x over previous
//
#include <hip/hip_runtime.h>
#include <hip/hip_bf16.h>

#define D 128

typedef __attribute__((ext_vector_type(8))) short short8;
typedef __attribute__((ext_vector_type(4))) float float4v;

__device__ __forceinline__ float4v mfma16(short8 a, short8 b, float4v c) {
  return __builtin_amdgcn_mfma_f32_16x16x32_bf16(a, b, c, 0, 0, 0);
}
__device__ __forceinline__ float b2f(__hip_bfloat16 x) { return __bfloat162float(x); }
__device__ __forceinline__ __hip_bfloat16 f2b(float x) { return __float2bfloat16(x); }
__device__ __forceinline__ unsigned short f2b_bits(float x) {
  __hip_bfloat16 h = __float2bfloat16(x);
  return *reinterpret_cast<unsigned short*>(&h);
}

__device__ __forceinline__ float ldf(const float* p, size_t i) { return p[i]; }
__device__ __forceinline__ float ldf(const __hip_bfloat16* p, size_t i) { return b2f(p[i]); }
__device__ __forceinline__ void stf(float* p, size_t i, float v) { p[i] = v; }
__device__ __forceinline__ void stf(__hip_bfloat16* p, size_t i, float v) { p[i] = f2b(v); }

// ---------------- fp32 -> bf16 casts ----------------
__global__ void k_cast(const float* __restrict__ in, __hip_bfloat16* __restrict__ out,
                       int n4) {
  int i = blockIdx.x * 256 + threadIdx.x;
  if (i < n4) {
    float4 v = ((const float4*)in)[i];
    __hip_bfloat16 o[4] = {f2b(v.x), f2b(v.y), f2b(v.z), f2b(v.w)};
    ((short4*)out)[i] = *(short4*)o;
  }
}

__global__ void k_cast_w(const float* __restrict__ wq, const float* __restrict__ wk,
                         const float* __restrict__ wv, const float* __restrict__ wo,
                         const float* __restrict__ w1, const float* __restrict__ w2,
                         __hip_bfloat16* __restrict__ oq, __hip_bfloat16* __restrict__ ok,
                         __hip_bfloat16* __restrict__ ov, __hip_bfloat16* __restrict__ oo,
                         __hip_bfloat16* __restrict__ o1, __hip_bfloat16* __restrict__ o2) {
  int i = blockIdx.x * 256 + threadIdx.x;  // 131072 total
  if (i < 16384) oq[i] = f2b(wq[i]);
  else if (i < 32768) ok[i - 16384] = f2b(wk[i - 16384]);
  else if (i < 49152) ov[i - 32768] = f2b(wv[i - 32768]);
  else if (i < 65536) oo[i - 49152] = f2b(wo[i - 49152]);
  else if (i < 98304) o1[i - 65536] = f2b(w1[i - 65536]);
  else o2[i - 98304] = f2b(w2[i - 98304]);
}

// ---------------- CSR build ----------------
__global__ void k_hist(const int* __restrict__ dst, int* __restrict__ deg, int E) {
  int e = blockIdx.x * 256 + threadIdx.x;
  if (e < E) atomicAdd(&deg[dst[e]], 1);
}

__global__ void k_scan1(const int* __restrict__ deg, int* __restrict__ offs,
                        int* __restrict__ bsum, int N) {
  __shared__ int sd[256];
  int b = blockIdx.x, t = threadIdx.x;
  int base = b * 1024 + t * 4;
  int v0 = 0, v1 = 0, v2 = 0, v3 = 0;
  if (base + 0 < N) v0 = deg[base + 0];
  if (base + 1 < N) v1 = deg[base + 1];
  if (base + 2 < N) v2 = deg[base + 2];
  if (base + 3 < N) v3 = deg[base + 3];
  int s = v0 + v1 + v2 + v3;
  sd[t] = s;
  __syncthreads();
  for (int ofs = 1; ofs < 256; ofs <<= 1) {
    int x = (t >= ofs) ? sd[t - ofs] : 0;
    __syncthreads();
    sd[t] += x;
    __syncthreads();
  }
  int run = sd[t] - s;  // exclusive prefix for this thread
  if (base + 0 < N) offs[base + 0] = run; run += v0;
  if (base + 1 < N) offs[base + 1] = run; run += v1;
  if (base + 2 < N) offs[base + 2] = run; run += v2;
  if (base + 3 < N) offs[base + 3] = run;
  if (t == 255) bsum[b] = sd[255];
}

__global__ void k_scan2(int* __restrict__ bsum, int B) {
  __shared__ int sd[256];
  int t = threadIdx.x;
  int v = (t < B) ? bsum[t] : 0;
  sd[t] = v;
  __syncthreads();
  for (int ofs = 1; ofs < 256; ofs <<= 1) {
    int x = (t >= ofs) ? sd[t - ofs] : 0;
    __syncthreads();
    sd[t] += x;
    __syncthreads();
  }
  if (t < B) bsum[t] = sd[t] - v;  // exclusive
}

__global__ void k_scan3(int* __restrict__ offs, int* __restrict__ cur,
                        const int* __restrict__ bsum, int N) {
  int b = blockIdx.x, t = threadIdx.x;
  int add = bsum[b];
  int base = b * 1024 + t * 4;
#pragma unroll
  for (int j = 0; j < 4; ++j) {
    int i = base + j;
    if (i < N) { int o = offs[i] + add; offs[i] = o; cur[i] = o; }
  }
}

__global__ void k_fill(const int* __restrict__ src, const int* __restrict__ dst,
                       int* __restrict__ cur, int* __restrict__ csr, int E) {
  int e = blockIdx.x * 256 + threadIdx.x;
  if (e < E) {
    int p = atomicAdd(&cur[dst[e]], 1);
    csr[p] = src[e];
  }
}

// ------- fused QKV GEMM: one A-fragment feeds 3 MFMAs; K/V stored interleaved -------
__global__ __launch_bounds__(64) void gemm_qkv(const short* __restrict__ A,
                                               const short* __restrict__ Bq,
                                               const short* __restrict__ Bk,
                                               const short* __restrict__ Bv,
                                               __hip_bfloat16* __restrict__ Q,
                                               unsigned int* __restrict__ KV,  // N x 128 uints
                                               int Nrow) {
  const int lane = threadIdx.x & 63;
  const int ct = blockIdx.y;  // 0..7
  const int n = lane & 15, quad = lane >> 4;
  short8 fq[4], fk[4], fv[4];
#pragma unroll
  for (int c = 0; c < 4; ++c) {
    short8 tq, tk, tv;
#pragma unroll
    for (int j = 0; j < 8; ++j) {
      int k = (c * 32 + quad * 8 + j) * 128 + ct * 16 + n;
      tq[j] = Bq[k]; tk[j] = Bk[k]; tv[j] = Bv[k];
    }
    fq[c] = tq; fk[c] = tk; fv[c] = tv;
  }
  int ntiles = Nrow >> 4;
  for (int rt = blockIdx.x; rt < ntiles; rt += gridDim.x) {
    float4v aq = {0.f, 0.f, 0.f, 0.f}, ak = aq, av = aq;
    const short* Ap = A + (size_t)(rt * 16 + n) * 128 + quad * 8;
#pragma unroll
    for (int c = 0; c < 4; ++c) {
      short8 a = *(const short8*)(Ap + c * 32);
      aq = mfma16(a, fq[c], aq);
      ak = mfma16(a, fk[c], ak);
      av = mfma16(a, fv[c], av);
    }
#pragma unroll
    for (int r = 0; r < 4; ++r) {
      int grow = rt * 16 + quad * 4 + r;
      int col = ct * 16 + n;
      Q[(size_t)grow * 128 + col] = f2b(aq[r]);
      unsigned int w = (unsigned int)f2b_bits(ak[r]) |
                       ((unsigned int)f2b_bits(av[r]) << 16);
      KV[(size_t)grow * 128 + col] = w;
    }
  }
}

// ---------------- GEMM (per-wave NCT x 16-col tiles, B frags in regs) ----------------
template <int K, bool RELU, int NCT>
__global__ __launch_bounds__(64) void gemm_plain(const short* __restrict__ A,
                                                 const short* __restrict__ B,
                                                 const float* __restrict__ bias,
                                                 __hip_bfloat16* __restrict__ Out,
                                                 int Nrow, int M) {
  const int lane = threadIdx.x & 63;
  const int ct0 = blockIdx.y * NCT;
  const int n = lane & 15, quad = lane >> 4;
  short8 bfr[NCT][K / 32];
#pragma unroll
  for (int c2 = 0; c2 < NCT; ++c2)
#pragma unroll
    for (int c = 0; c < K / 32; ++c) {
      short8 tmp;
#pragma unroll
      for (int j = 0; j < 8; ++j)
        tmp[j] = B[(size_t)(c * 32 + quad * 8 + j) * M + (ct0 + c2) * 16 + n];
      bfr[c2][c] = tmp;
    }
  float biasv[NCT];
#pragma unroll
  for (int c2 = 0; c2 < NCT; ++c2) biasv[c2] = bias ? bias[(ct0 + c2) * 16 + n] : 0.f;
  int ntiles = Nrow >> 4;
  for (int rt = blockIdx.x; rt < ntiles; rt += gridDim.x) {
    float4v acc[NCT];
#pragma unroll
    for (int c2 = 0; c2 < NCT; ++c2) acc[c2] = (float4v){0.f, 0.f, 0.f, 0.f};
    const short* Ap = A + (size_t)(rt * 16 + n) * K + quad * 8;
#pragma unroll
    for (int c = 0; c < K / 32; ++c) {
      short8 a = *(const short8*)(Ap + c * 32);
#pragma unroll
      for (int c2 = 0; c2 < NCT; ++c2) acc[c2] = mfma16(a, bfr[c2][c], acc[c2]);
    }
#pragma unroll
    for (int c2 = 0; c2 < NCT; ++c2)
#pragma unroll
      for (int r = 0; r < 4; ++r) {
        int grow = rt * 16 + quad * 4 + r;
        float v = acc[c2][r] + biasv[c2];
        if (RELU) v = fmaxf(v, 0.f);
        Out[(size_t)grow * M + (ct0 + c2) * 16 + n] = f2b(v);
      }
  }
}

// ------ GEMM + bias + residual + LayerNorm (M=128 fixed), fp32/bf16 generic ------
template <int K, typename TR, typename TO>
__global__ __launch_bounds__(512) void ln_gemm(const short* __restrict__ A,
                                               const short* __restrict__ B,
                                               const float* __restrict__ bias,
                                               const TR* __restrict__ resid,
                                               const float* __restrict__ gam,
                                               const float* __restrict__ bet,
                                               TO* __restrict__ Out, int Nrow) {
  __shared__ float tile[16][132];
  const int t = threadIdx.x;
  const int lane = t & 63;
  const int ct = t >> 6;  // wave id = col tile (8 waves x 16 cols = 128)
  const int n = lane & 15, quad = lane >> 4;
  short8 bfr[K / 32];
#pragma unroll
  for (int c = 0; c < K / 32; ++c) {
    short8 tmp;
#pragma unroll
    for (int j = 0; j < 8; ++j)
      tmp[j] = B[(size_t)(c * 32 + quad * 8 + j) * 128 + ct * 16 + n];
    bfr[c] = tmp;
  }
  float biasv = bias[ct * 16 + n];
  const int row2 = t >> 5, sub = t & 31;
  float ga0 = gam[sub],      ga1 = gam[sub + 32];
  float ga2 = gam[sub + 64], ga3 = gam[sub + 96];
  float be0 = bet[sub],      be1 = bet[sub + 32];
  float be2 = bet[sub + 64], be3 = bet[sub + 96];
  int ntiles = Nrow >> 4;
  for (int rt = blockIdx.x; rt < ntiles; rt += gridDim.x) {
    float4v acc = {0.f, 0.f, 0.f, 0.f};
    const short* Ap = A + (size_t)(rt * 16 + n) * K + quad * 8;
#pragma unroll
    for (int c = 0; c < K / 32; ++c)
      acc = mfma16(*(const short8*)(Ap + c * 32), bfr[c], acc);
#pragma unroll
    for (int r = 0; r < 4; ++r) {
      int rr = quad * 4 + r;
      size_t g = (size_t)(rt * 16 + rr) * 128 + ct * 16 + n;
      tile[rr][ct * 16 + n] = acc[r] + biasv + ldf(resid, g);
    }
    __syncthreads();
    float x0 = tile[row2][sub], x1 = tile[row2][sub + 32];
    float x2 = tile[row2][sub + 64], x3 = tile[row2][sub + 96];
    float s = x0 + x1 + x2 + x3;
    float s2 = x0 * x0 + x1 * x1 + x2 * x2 + x3 * x3;
#pragma unroll
    for (int o = 16; o >= 1; o >>= 1) {
      s += __shfl_xor(s, o);
      s2 += __shfl_xor(s2, o);
    }
    float mean = s * 0.0078125f;
    float var = s2 * 0.0078125f - mean * mean;
    float rstd = rsqrtf(var + 1e-5f);
    size_t base = (size_t)(rt * 16 + row2) * 128;
    stf(Out, base + sub,      (x0 - mean) * rstd * ga0 + be0);
    stf(Out, base + sub + 32, (x1 - mean) * rstd * ga1 + be1);
    stf(Out, base + sub + 64, (x2 - mean) * rstd * ga2 + be2);
    stf(Out, base + sub + 96, (x3 - mean) * rstd * ga3 + be3);
    __syncthreads();
  }
}

// ---------------- dst-centric attention aggregation (v2) ----------------
// One wave per node. Thread t owns dims {2t, 2t+1}; head = t>>3 (8 lanes/head).
// KV rows are (K_d, V_d) interleaved bf16 -> one dwordx2 gather per edge per lane.
__device__ __forceinline__ void edge_step(uint2 w, float q0, float q1,
                                          float& a0, float& a1, float& z) {
  float k0 = __uint_as_float(w.x << 16);
  float v0 = __uint_as_float(w.x & 0xffff0000u);
  float k1 = __uint_as_float(w.y << 16);
  float v1 = __uint_as_float(w.y & 0xffff0000u);
  float p = q0 * k0 + q1 * k1;
  p += __shfl_xor(p, 1);
  p += __shfl_xor(p, 2);
  p += __shfl_xor(p, 4);
  float sc = __expf(fminf(fmaxf(p * 0.25f, -5.f), 5.f));
  a0 = fmaf(sc, v0, a0);
  a1 = fmaf(sc, v1, a1);
  z += sc;
}

__global__ __launch_bounds__(64) void attn_agg2(const unsigned int* __restrict__ Qu,
                                                const uint2* __restrict__ KV,
                                                const int* __restrict__ offs,
                                                const int* __restrict__ deg,
                                                const int* __restrict__ csr,
                                                unsigned int* __restrict__ ATu) {
  const int node = blockIdx.x;
  const int t = threadIdx.x;  // 0..63
  unsigned int qw = Qu[(size_t)node * 64 + t];
  float q0 = __uint_as_float(qw << 16);
  float q1 = __uint_as_float(qw & 0xffff0000u);
  const int st = offs[node];
  const int dg = deg[node];
  float a0 = 0.f, a1 = 0.f, z = 0.f;
  int i = 0;
  int s0 = 0, s1 = 0, s2 = 0, s3 = 0;
  if (dg >= 4) { s0 = csr[st]; s1 = csr[st + 1]; s2 = csr[st + 2]; s3 = csr[st + 3]; }
  while (i + 4 <= dg) {
    uint2 w0 = KV[(size_t)s0 * 64 + t];
    uint2 w1 = KV[(size_t)s1 * 64 + t];
    uint2 w2 = KV[(size_t)s2 * 64 + t];
    uint2 w3 = KV[(size_t)s3 * 64 + t];
    i += 4;
    int n0 = s0, n1 = s1, n2 = s2, n3 = s3;
    if (i + 4 <= dg) {
      n0 = csr[st + i]; n1 = csr[st + i + 1];
      n2 = csr[st + i + 2]; n3 = csr[st + i + 3];
    }
    edge_step(w0, q0, q1, a0, a1, z);
    edge_step(w1, q0, q1, a0, a1, z);
    edge_step(w2, q0, q1, a0, a1, z);
    edge_step(w3, q0, q1, a0, a1, z);
    s0 = n0; s1 = n1; s2 = n2; s3 = n3;
  }
  for (; i < dg; ++i) {
    int s = csr[st + i];
    uint2 w = KV[(size_t)s * 64 + t];
    edge_step(w, q0, q1, a0, a1, z);
  }
  float inv = (z > 0.f) ? (1.f / z) : 1.f;
  float o0 = a0 * inv, o1 = a1 * inv;
  ATu[(size_t)node * 64 + t] =
      (unsigned int)f2b_bits(o0) | ((unsigned int)f2b_bits(o1) << 16);
}

// ---------------- launch ----------------
extern "C" void kernel_launch(void* const* d_in, const int* in_sizes, int n_in,
                              void* d_out, int out_size, void* d_ws, size_t ws_size,
                              hipStream_t stream) {
  const float* h = (const float*)d_in[0];
  const int* src = (const int*)d_in[1];
  const int* dst = (const int*)d_in[2];
  const float* Wq = (const float*)d_in[3];
  const float* Wk = (const float*)d_in[4];
  const float* Wv = (const float*)d_in[5];
  const float* Wo = (const float*)d_in[6];
  const float* bo = (const float*)d_in[7];
  const float* g1 = (const float*)d_in[8];
  const float* b1 = (const float*)d_in[9];
  const float* g2 = (const float*)d_in[10];
  const float* b2 = (const float*)d_in[11];
  const float* W1 = (const float*)d_in[12];
  const float* c1 = (const float*)d_in[13];
  const float* W2 = (const float*)d_in[14];
  const float* c2 = (const float*)d_in[15];

  const int N = in_sizes[0] / D;
  const int E = in_sizes[1];

  char* p = (char*)d_ws;
  auto carve = [&](size_t bytes) {
    char* r = p;
    p += (bytes + 255) & ~(size_t)255;
    return r;
  };
  short* hb = (short*)carve((size_t)N * D * 2);        // bf16 h; later AT
  short* Qb = (short*)carve((size_t)N * D * 2);        // later hh
  unsigned int* KVb = (unsigned int*)carve((size_t)N * D * 4);  // interleaved K,V; later tmid
  short* wq = (short*)carve(16384 * 2);
  short* wk = (short*)carve(16384 * 2);
  short* wv = (short*)carve(16384 * 2);
  short* wo = (short*)carve(16384 * 2);
  short* w1 = (short*)carve(32768 * 2);
  short* w2 = (short*)carve(32768 * 2);
  int* deg = (int*)carve((size_t)N * 4);
  int* offs = (int*)carve((size_t)N * 4);
  int* cur = (int*)carve((size_t)N * 4);
  int* bsum = (int*)carve(1024);
  int* csr = (int*)carve((size_t)E * 4);
  short* ATb = hb;           // alias: h-bf16 dead after qkv gemm
  short* hh = Qb;            // alias: Q dead after attn_agg
  short* tmid = (short*)KVb; // alias: N*256 bf16; K/V dead after attn_agg

  hipMemsetAsync(deg, 0, (size_t)N * 4, stream);
  int eb = (E + 255) / 256;
  k_hist<<<eb, 256, 0, stream>>>(dst, deg, E);
  int B1 = (N + 1023) / 1024;
  k_scan1<<<B1, 256, 0, stream>>>(deg, offs, bsum, N);
  k_scan2<<<1, 256, 0, stream>>>(bsum, B1);
  k_scan3<<<B1, 256, 0, stream>>>(offs, cur, bsum, N);
  k_fill<<<eb, 256, 0, stream>>>(src, dst, cur, csr, E);

  int n4 = N * D / 4;
  k_cast<<<(n4 + 255) / 256, 256, 0, stream>>>(h, (__hip_bfloat16*)hb, n4);
  k_cast_w<<<512, 256, 0, stream>>>(Wq, Wk, Wv, Wo, W1, W2,
                                    (__hip_bfloat16*)wq, (__hip_bfloat16*)wk,
                                    (__hip_bfloat16*)wv, (__hip_bfloat16*)wo,
                                    (__hip_bfloat16*)w1, (__hip_bfloat16*)w2);

  gemm_qkv<<<dim3(1024, 8), 64, 0, stream>>>(hb, wq, wk, wv,
                                             (__hip_bfloat16*)Qb, KVb, N);

  attn_agg2<<<N, 64, 0, stream>>>((const unsigned int*)Qb, (const uint2*)KVb,
                                  offs, deg, csr, (unsigned int*)ATb);

  ln_gemm<128, float, __hip_bfloat16><<<1024, 512, 0, stream>>>(
      ATb, wo, bo, h, g1, b1, (__hip_bfloat16*)hh, N);
  gemm_plain<128, true, 2><<<dim3(1024, 8), 64, 0, stream>>>(
      hh, w1, c1, (__hip_bfloat16*)tmid, N, 256);
  ln_gemm<256, __hip_bfloat16, float><<<1024, 512, 0, stream>>>(
      tmid, w2, c2, (const __hip_bfloat16*)hh, g2, b2, (float*)d_out, N);
}

// Round 4
// 482.169 us; speedup vs baseline: 1.6393x; 1.2762x over previous
//
#include <hip/hip_runtime.h>
#include <hip/hip_bf16.h>

#define D 128

typedef __attribute__((ext_vector_type(8))) short short8;
typedef __attribute__((ext_vector_type(4))) float float4v;

__device__ __forceinline__ float4v mfma16(short8 a, short8 b, float4v c) {
  return __builtin_amdgcn_mfma_f32_16x16x32_bf16(a, b, c, 0, 0, 0);
}
__device__ __forceinline__ float b2f(__hip_bfloat16 x) { return __bfloat162float(x); }
__device__ __forceinline__ __hip_bfloat16 f2b(float x) { return __float2bfloat16(x); }
__device__ __forceinline__ unsigned short f2b_bits(float x) {
  __hip_bfloat16 h = __float2bfloat16(x);
  return *reinterpret_cast<unsigned short*>(&h);
}

__device__ __forceinline__ float ldf(const float* p, size_t i) { return p[i]; }
__device__ __forceinline__ float ldf(const __hip_bfloat16* p, size_t i) { return b2f(p[i]); }
__device__ __forceinline__ void stf(float* p, size_t i, float v) { p[i] = v; }
__device__ __forceinline__ void stf(__hip_bfloat16* p, size_t i, float v) { p[i] = f2b(v); }

// ---------------- fp32 -> bf16 casts ----------------
__global__ void k_cast(const float* __restrict__ in, __hip_bfloat16* __restrict__ out,
                       int n4) {
  int i = blockIdx.x * 256 + threadIdx.x;
  if (i < n4) {
    float4 v = ((const float4*)in)[i];
    __hip_bfloat16 o[4] = {f2b(v.x), f2b(v.y), f2b(v.z), f2b(v.w)};
    ((short4*)out)[i] = *(short4*)o;
  }
}

__global__ void k_cast_w(const float* __restrict__ wq, const float* __restrict__ wk,
                         const float* __restrict__ wv, const float* __restrict__ wo,
                         const float* __restrict__ w1, const float* __restrict__ w2,
                         __hip_bfloat16* __restrict__ oq, __hip_bfloat16* __restrict__ ok,
                         __hip_bfloat16* __restrict__ ov, __hip_bfloat16* __restrict__ oo,
                         __hip_bfloat16* __restrict__ o1, __hip_bfloat16* __restrict__ o2) {
  int i = blockIdx.x * 256 + threadIdx.x;  // 131072 total
  if (i < 16384) oq[i] = f2b(wq[i]);
  else if (i < 32768) ok[i - 16384] = f2b(wk[i - 16384]);
  else if (i < 49152) ov[i - 32768] = f2b(wv[i - 32768]);
  else if (i < 65536) oo[i - 49152] = f2b(wo[i - 49152]);
  else if (i < 98304) o1[i - 65536] = f2b(w1[i - 65536]);
  else o2[i - 98304] = f2b(w2[i - 98304]);
}

// ---------------- CSR build via two-phase binning (bucket = dst>>8) ----------------
#define MAXB 512

__global__ void k_bhist(const int* __restrict__ dst, int* __restrict__ bh, int E) {
  __shared__ int cnt[MAXB];
  for (int i = threadIdx.x; i < MAXB; i += 256) cnt[i] = 0;
  __syncthreads();
  for (int e = blockIdx.x * 256 + threadIdx.x; e < E; e += gridDim.x * 256)
    atomicAdd(&cnt[dst[e] >> 8], 1);
  __syncthreads();
  for (int i = threadIdx.x; i < MAXB; i += 256)
    if (cnt[i]) atomicAdd(&bh[i], cnt[i]);
}

__global__ void k_bscan(const int* __restrict__ bh, int* __restrict__ bbase,
                        int* __restrict__ bcur, int B) {
  __shared__ int sd[MAXB];
  int t = threadIdx.x;
  int v = (t < B) ? bh[t] : 0;
  sd[t] = v;
  __syncthreads();
  for (int o = 1; o < MAXB; o <<= 1) {
    int x = (t >= o) ? sd[t - o] : 0;
    __syncthreads();
    sd[t] += x;
    __syncthreads();
  }
  if (t < B) {
    int e = sd[t] - v;
    bbase[t] = e;
    bcur[t] = e;
  }
}

// each block bins 4096 edges into contiguous per-bucket runs
__global__ __launch_bounds__(256) void k_bin(const int* __restrict__ src,
                                             const int* __restrict__ dst,
                                             int* __restrict__ bcur,
                                             uint2* __restrict__ binned, int E) {
  __shared__ int cnt[MAXB];
  __shared__ int base[MAXB];
  const int t = threadIdx.x;
  const int e0 = blockIdx.x * 4096;
  for (int i = t; i < MAXB; i += 256) cnt[i] = 0;
  __syncthreads();
  int myb[16], myr[16], ms[16], md[16];
#pragma unroll
  for (int j = 0; j < 16; ++j) {
    int e = e0 + j * 256 + t;
    if (e < E) {
      int d = dst[e];
      ms[j] = src[e];
      md[j] = d;
      int b = d >> 8;
      myb[j] = b;
      myr[j] = atomicAdd(&cnt[b], 1);
    } else {
      myb[j] = -1;
    }
  }
  __syncthreads();
  for (int i = t; i < MAXB; i += 256)
    base[i] = cnt[i] ? atomicAdd(&bcur[i], cnt[i]) : 0;
  __syncthreads();
#pragma unroll
  for (int j = 0; j < 16; ++j)
    if (myb[j] >= 0)
      binned[(size_t)base[myb[j]] + myr[j]] = make_uint2((unsigned)ms[j], (unsigned)md[j]);
}

// one block per bucket: per-node deg/offs + LDS-local fine scatter into csr
__global__ __launch_bounds__(256) void k_fine(const uint2* __restrict__ binned,
                                              const int* __restrict__ bh,
                                              const int* __restrict__ bbase,
                                              int* __restrict__ deg,
                                              int* __restrict__ offs,
                                              int* __restrict__ csr, int N) {
  __shared__ int cnt[256];
  __shared__ int cur[256];
  __shared__ int sd[256];
  const int b = blockIdx.x, t = threadIdx.x;
  const int node0 = b << 8;
  cnt[t] = 0;
  __syncthreads();
  const int s0 = bbase[b], len = bh[b];
  for (int i = t; i < len; i += 256) atomicAdd(&cnt[binned[(size_t)s0 + i].y & 255], 1);
  __syncthreads();
  int v = cnt[t];
  sd[t] = v;
  __syncthreads();
  for (int o = 1; o < 256; o <<= 1) {
    int x = (t >= o) ? sd[t - o] : 0;
    __syncthreads();
    sd[t] += x;
    __syncthreads();
  }
  int excl = sd[t] - v;
  cur[t] = excl;
  int node = node0 + t;
  if (node < N) {
    deg[node] = v;
    offs[node] = s0 + excl;
  }
  __syncthreads();
  for (int i = t; i < len; i += 256) {
    uint2 ed = binned[(size_t)s0 + i];
    int p = atomicAdd(&cur[ed.y & 255], 1);
    csr[s0 + p] = (int)ed.x;
  }
}

// ------- fused QKV GEMM: one A-fragment feeds 3 MFMAs; K/V stored interleaved -------
__global__ __launch_bounds__(64) void gemm_qkv(const short* __restrict__ A,
                                               const short* __restrict__ Bq,
                                               const short* __restrict__ Bk,
                                               const short* __restrict__ Bv,
                                               __hip_bfloat16* __restrict__ Q,
                                               unsigned int* __restrict__ KV,  // N x 128 uints
                                               int Nrow) {
  const int lane = threadIdx.x & 63;
  const int ct = blockIdx.y;  // 0..7
  const int n = lane & 15, quad = lane >> 4;
  short8 fq[4], fk[4], fv[4];
#pragma unroll
  for (int c = 0; c < 4; ++c) {
    short8 tq, tk, tv;
#pragma unroll
    for (int j = 0; j < 8; ++j) {
      int k = (c * 32 + quad * 8 + j) * 128 + ct * 16 + n;
      tq[j] = Bq[k]; tk[j] = Bk[k]; tv[j] = Bv[k];
    }
    fq[c] = tq; fk[c] = tk; fv[c] = tv;
  }
  int ntiles = Nrow >> 4;
  for (int rt = blockIdx.x; rt < ntiles; rt += gridDim.x) {
    float4v aq = {0.f, 0.f, 0.f, 0.f}, ak = aq, av = aq;
    const short* Ap = A + (size_t)(rt * 16 + n) * 128 + quad * 8;
#pragma unroll
    for (int c = 0; c < 4; ++c) {
      short8 a = *(const short8*)(Ap + c * 32);
      aq = mfma16(a, fq[c], aq);
      ak = mfma16(a, fk[c], ak);
      av = mfma16(a, fv[c], av);
    }
#pragma unroll
    for (int r = 0; r < 4; ++r) {
      int grow = rt * 16 + quad * 4 + r;
      int col = ct * 16 + n;
      Q[(size_t)grow * 128 + col] = f2b(aq[r]);
      unsigned int w = (unsigned int)f2b_bits(ak[r]) |
                       ((unsigned int)f2b_bits(av[r]) << 16);
      KV[(size_t)grow * 128 + col] = w;
    }
  }
}

// ---------------- GEMM (per-wave NCT x 16-col tiles, B frags in regs) ----------------
template <int K, bool RELU, int NCT>
__global__ __launch_bounds__(64) void gemm_plain(const short* __restrict__ A,
                                                 const short* __restrict__ B,
                                                 const float* __restrict__ bias,
                                                 __hip_bfloat16* __restrict__ Out,
                                                 int Nrow, int M) {
  const int lane = threadIdx.x & 63;
  const int ct0 = blockIdx.y * NCT;
  const int n = lane & 15, quad = lane >> 4;
  short8 bfr[NCT][K / 32];
#pragma unroll
  for (int c2 = 0; c2 < NCT; ++c2)
#pragma unroll
    for (int c = 0; c < K / 32; ++c) {
      short8 tmp;
#pragma unroll
      for (int j = 0; j < 8; ++j)
        tmp[j] = B[(size_t)(c * 32 + quad * 8 + j) * M + (ct0 + c2) * 16 + n];
      bfr[c2][c] = tmp;
    }
  float biasv[NCT];
#pragma unroll
  for (int c2 = 0; c2 < NCT; ++c2) biasv[c2] = bias ? bias[(ct0 + c2) * 16 + n] : 0.f;
  int ntiles = Nrow >> 4;
  for (int rt = blockIdx.x; rt < ntiles; rt += gridDim.x) {
    float4v acc[NCT];
#pragma unroll
    for (int c2 = 0; c2 < NCT; ++c2) acc[c2] = (float4v){0.f, 0.f, 0.f, 0.f};
    const short* Ap = A + (size_t)(rt * 16 + n) * K + quad * 8;
#pragma unroll
    for (int c = 0; c < K / 32; ++c) {
      short8 a = *(const short8*)(Ap + c * 32);
#pragma unroll
      for (int c2 = 0; c2 < NCT; ++c2) acc[c2] = mfma16(a, bfr[c2][c], acc[c2]);
    }
#pragma unroll
    for (int c2 = 0; c2 < NCT; ++c2)
#pragma unroll
      for (int r = 0; r < 4; ++r) {
        int grow = rt * 16 + quad * 4 + r;
        float v = acc[c2][r] + biasv[c2];
        if (RELU) v = fmaxf(v, 0.f);
        Out[(size_t)grow * M + (ct0 + c2) * 16 + n] = f2b(v);
      }
  }
}

// ------ GEMM + bias + residual + LayerNorm (M=128 fixed), fp32/bf16 generic ------
template <int K, typename TR, typename TO>
__global__ __launch_bounds__(512) void ln_gemm(const short* __restrict__ A,
                                               const short* __restrict__ B,
                                               const float* __restrict__ bias,
                                               const TR* __restrict__ resid,
                                               const float* __restrict__ gam,
                                               const float* __restrict__ bet,
                                               TO* __restrict__ Out, int Nrow) {
  __shared__ float tile[16][132];
  const int t = threadIdx.x;
  const int lane = t & 63;
  const int ct = t >> 6;  // wave id = col tile (8 waves x 16 cols = 128)
  const int n = lane & 15, quad = lane >> 4;
  short8 bfr[K / 32];
#pragma unroll
  for (int c = 0; c < K / 32; ++c) {
    short8 tmp;
#pragma unroll
    for (int j = 0; j < 8; ++j)
      tmp[j] = B[(size_t)(c * 32 + quad * 8 + j) * 128 + ct * 16 + n];
    bfr[c] = tmp;
  }
  float biasv = bias[ct * 16 + n];
  const int row2 = t >> 5, sub = t & 31;
  float ga0 = gam[sub],      ga1 = gam[sub + 32];
  float ga2 = gam[sub + 64], ga3 = gam[sub + 96];
  float be0 = bet[sub],      be1 = bet[sub + 32];
  float be2 = bet[sub + 64], be3 = bet[sub + 96];
  int ntiles = Nrow >> 4;
  for (int rt = blockIdx.x; rt < ntiles; rt += gridDim.x) {
    float4v acc = {0.f, 0.f, 0.f, 0.f};
    const short* Ap = A + (size_t)(rt * 16 + n) * K + quad * 8;
#pragma unroll
    for (int c = 0; c < K / 32; ++c)
      acc = mfma16(*(const short8*)(Ap + c * 32), bfr[c], acc);
#pragma unroll
    for (int r = 0; r < 4; ++r) {
      int rr = quad * 4 + r;
      size_t g = (size_t)(rt * 16 + rr) * 128 + ct * 16 + n;
      tile[rr][ct * 16 + n] = acc[r] + biasv + ldf(resid, g);
    }
    __syncthreads();
    float x0 = tile[row2][sub], x1 = tile[row2][sub + 32];
    float x2 = tile[row2][sub + 64], x3 = tile[row2][sub + 96];
    float s = x0 + x1 + x2 + x3;
    float s2 = x0 * x0 + x1 * x1 + x2 * x2 + x3 * x3;
#pragma unroll
    for (int o = 16; o >= 1; o >>= 1) {
      s += __shfl_xor(s, o);
      s2 += __shfl_xor(s2, o);
    }
    float mean = s * 0.0078125f;
    float var = s2 * 0.0078125f - mean * mean;
    float rstd = rsqrtf(var + 1e-5f);
    size_t base = (size_t)(rt * 16 + row2) * 128;
    stf(Out, base + sub,      (x0 - mean) * rstd * ga0 + be0);
    stf(Out, base + sub + 32, (x1 - mean) * rstd * ga1 + be1);
    stf(Out, base + sub + 64, (x2 - mean) * rstd * ga2 + be2);
    stf(Out, base + sub + 96, (x3 - mean) * rstd * ga3 + be3);
    __syncthreads();
  }
}

// ---------------- dst-centric attention aggregation (v2) ----------------
__device__ __forceinline__ void edge_step(uint2 w, float q0, float q1,
                                          float& a0, float& a1, float& z) {
  float k0 = __uint_as_float(w.x << 16);
  float v0 = __uint_as_float(w.x & 0xffff0000u);
  float k1 = __uint_as_float(w.y << 16);
  float v1 = __uint_as_float(w.y & 0xffff0000u);
  float p = q0 * k0 + q1 * k1;
  p += __shfl_xor(p, 1);
  p += __shfl_xor(p, 2);
  p += __shfl_xor(p, 4);
  float sc = __expf(fminf(fmaxf(p * 0.25f, -5.f), 5.f));
  a0 = fmaf(sc, v0, a0);
  a1 = fmaf(sc, v1, a1);
  z += sc;
}

__global__ __launch_bounds__(64) void attn_agg2(const unsigned int* __restrict__ Qu,
                                                const uint2* __restrict__ KV,
                                                const int* __restrict__ offs,
                                                const int* __restrict__ deg,
                                                const int* __restrict__ csr,
                                                unsigned int* __restrict__ ATu) {
  const int node = blockIdx.x;
  const int t = threadIdx.x;  // 0..63
  unsigned int qw = Qu[(size_t)node * 64 + t];
  float q0 = __uint_as_float(qw << 16);
  float q1 = __uint_as_float(qw & 0xffff0000u);
  const int st = offs[node];
  const int dg = deg[node];
  float a0 = 0.f, a1 = 0.f, z = 0.f;
  int i = 0;
  int s0 = 0, s1 = 0, s2 = 0, s3 = 0;
  if (dg >= 4) { s0 = csr[st]; s1 = csr[st + 1]; s2 = csr[st + 2]; s3 = csr[st + 3]; }
  while (i + 4 <= dg) {
    uint2 w0 = KV[(size_t)s0 * 64 + t];
    uint2 w1 = KV[(size_t)s1 * 64 + t];
    uint2 w2 = KV[(size_t)s2 * 64 + t];
    uint2 w3 = KV[(size_t)s3 * 64 + t];
    i += 4;
    int n0 = s0, n1 = s1, n2 = s2, n3 = s3;
    if (i + 4 <= dg) {
      n0 = csr[st + i]; n1 = csr[st + i + 1];
      n2 = csr[st + i + 2]; n3 = csr[st + i + 3];
    }
    edge_step(w0, q0, q1, a0, a1, z);
    edge_step(w1, q0, q1, a0, a1, z);
    edge_step(w2, q0, q1, a0, a1, z);
    edge_step(w3, q0, q1, a0, a1, z);
    s0 = n0; s1 = n1; s2 = n2; s3 = n3;
  }
  for (; i < dg; ++i) {
    int s = csr[st + i];
    uint2 w = KV[(size_t)s * 64 + t];
    edge_step(w, q0, q1, a0, a1, z);
  }
  float inv = (z > 0.f) ? (1.f / z) : 1.f;
  float o0 = a0 * inv, o1 = a1 * inv;
  ATu[(size_t)node * 64 + t] =
      (unsigned int)f2b_bits(o0) | ((unsigned int)f2b_bits(o1) << 16);
}

// ---------------- launch ----------------
extern "C" void kernel_launch(void* const* d_in, const int* in_sizes, int n_in,
                              void* d_out, int out_size, void* d_ws, size_t ws_size,
                              hipStream_t stream) {
  const float* h = (const float*)d_in[0];
  const int* src = (const int*)d_in[1];
  const int* dst = (const int*)d_in[2];
  const float* Wq = (const float*)d_in[3];
  const float* Wk = (const float*)d_in[4];
  const float* Wv = (const float*)d_in[5];
  const float* Wo = (const float*)d_in[6];
  const float* bo = (const float*)d_in[7];
  const float* g1 = (const float*)d_in[8];
  const float* b1 = (const float*)d_in[9];
  const float* g2 = (const float*)d_in[10];
  const float* b2 = (const float*)d_in[11];
  const float* W1 = (const float*)d_in[12];
  const float* c1 = (const float*)d_in[13];
  const float* W2 = (const float*)d_in[14];
  const float* c2 = (const float*)d_in[15];

  const int N = in_sizes[0] / D;
  const int E = in_sizes[1];
  const int B = (N + 255) >> 8;

  char* p = (char*)d_ws;
  auto carve = [&](size_t bytes) {
    char* r = p;
    p += (bytes + 255) & ~(size_t)255;
    return r;
  };
  short* hb = (short*)carve((size_t)N * D * 2);        // bf16 h; later AT
  short* Qb = (short*)carve((size_t)N * D * 2);        // later hh
  unsigned int* KVb = (unsigned int*)carve((size_t)N * D * 4);  // interleaved K,V; later tmid
  short* wq = (short*)carve(16384 * 2);
  short* wk = (short*)carve(16384 * 2);
  short* wv = (short*)carve(16384 * 2);
  short* wo = (short*)carve(16384 * 2);
  short* w1 = (short*)carve(32768 * 2);
  short* w2 = (short*)carve(32768 * 2);
  int* deg = (int*)carve((size_t)N * 4);
  int* offs = (int*)carve((size_t)N * 4);
  int* bh = (int*)carve(MAXB * 4);
  int* bbase = (int*)carve(MAXB * 4);
  int* bcur = (int*)carve(MAXB * 4);
  uint2* binned = (uint2*)carve((size_t)E * 8);
  int* csr = (int*)carve((size_t)E * 4);
  short* ATb = hb;           // alias: h-bf16 dead after qkv gemm
  short* hh = Qb;            // alias: Q dead after attn_agg
  short* tmid = (short*)KVb; // alias: N*256 bf16; K/V dead after attn_agg

  hipMemsetAsync(bh, 0, MAXB * 4, stream);
  k_bhist<<<1024, 256, 0, stream>>>(dst, bh, E);
  k_bscan<<<1, MAXB, 0, stream>>>(bh, bbase, bcur, B);
  k_bin<<<(E + 4095) / 4096, 256, 0, stream>>>(src, dst, bcur, binned, E);
  k_fine<<<B, 256, 0, stream>>>(binned, bh, bbase, deg, offs, csr, N);

  int n4 = N * D / 4;
  k_cast<<<(n4 + 255) / 256, 256, 0, stream>>>(h, (__hip_bfloat16*)hb, n4);
  k_cast_w<<<512, 256, 0, stream>>>(Wq, Wk, Wv, Wo, W1, W2,
                                    (__hip_bfloat16*)wq, (__hip_bfloat16*)wk,
                                    (__hip_bfloat16*)wv, (__hip_bfloat16*)wo,
                                    (__hip_bfloat16*)w1, (__hip_bfloat16*)w2);

  gemm_qkv<<<dim3(1024, 8), 64, 0, stream>>>(hb, wq, wk, wv,
                                             (__hip_bfloat16*)Qb, KVb, N);

  attn_agg2<<<N, 64, 0, stream>>>((const unsigned int*)Qb, (const uint2*)KVb,
                                  offs, deg, csr, (unsigned int*)ATb);

  ln_gemm<128, float, __hip_bfloat16><<<1024, 512, 0, stream>>>(
      ATb, wo, bo, h, g1, b1, (__hip_bfloat16*)hh, N);
  gemm_plain<128, true, 2><<<dim3(1024, 8), 64, 0, stream>>>(
      hh, w1, c1, (__hip_bfloat16*)tmid, N, 256);
  ln_gemm<256, __hip_bfloat16, float><<<1024, 512, 0, stream>>>(
      tmid, w2, c2, (const __hip_bfloat16*)hh, g2, b2, (float*)d_out, N);
}

// Round 5
// 472.938 us; speedup vs baseline: 1.6713x; 1.0195x over previous
//
#include <hip/hip_runtime.h>
#include <hip/hip_bf16.h>

#define D 128

typedef __attribute__((ext_vector_type(8))) short short8;
typedef __attribute__((ext_vector_type(4))) float float4v;

__device__ __forceinline__ float4v mfma16(short8 a, short8 b, float4v c) {
  return __builtin_amdgcn_mfma_f32_16x16x32_bf16(a, b, c, 0, 0, 0);
}
__device__ __forceinline__ float b2f(__hip_bfloat16 x) { return __bfloat162float(x); }
__device__ __forceinline__ __hip_bfloat16 f2b(float x) { return __float2bfloat16(x); }
__device__ __forceinline__ unsigned short f2b_bits(float x) {
  __hip_bfloat16 h = __float2bfloat16(x);
  return *reinterpret_cast<unsigned short*>(&h);
}

__device__ __forceinline__ float ldf(const float* p, size_t i) { return p[i]; }
__device__ __forceinline__ float ldf(const __hip_bfloat16* p, size_t i) { return b2f(p[i]); }
__device__ __forceinline__ void stf(float* p, size_t i, float v) { p[i] = v; }
__device__ __forceinline__ void stf(__hip_bfloat16* p, size_t i, float v) { p[i] = f2b(v); }

__device__ __forceinline__ void unpack2(unsigned w, float& lo, float& hi) {
  lo = __uint_as_float(w << 16);
  hi = __uint_as_float(w & 0xffff0000u);
}
__device__ __forceinline__ void unp8(uint4 w, float* q) {
  unpack2(w.x, q[0], q[1]);
  unpack2(w.y, q[2], q[3]);
  unpack2(w.z, q[4], q[5]);
  unpack2(w.w, q[6], q[7]);
}
__device__ __forceinline__ float dot8(uint4 w, const float* q) {
  float p = 0.f, lo, hi;
  unpack2(w.x, lo, hi); p = fmaf(q[0], lo, p); p = fmaf(q[1], hi, p);
  unpack2(w.y, lo, hi); p = fmaf(q[2], lo, p); p = fmaf(q[3], hi, p);
  unpack2(w.z, lo, hi); p = fmaf(q[4], lo, p); p = fmaf(q[5], hi, p);
  unpack2(w.w, lo, hi); p = fmaf(q[6], lo, p); p = fmaf(q[7], hi, p);
  return p;
}
__device__ __forceinline__ void fma8(uint4 w, float sc, float* a) {
  float lo, hi;
  unpack2(w.x, lo, hi); a[0] = fmaf(sc, lo, a[0]); a[1] = fmaf(sc, hi, a[1]);
  unpack2(w.y, lo, hi); a[2] = fmaf(sc, lo, a[2]); a[3] = fmaf(sc, hi, a[3]);
  unpack2(w.z, lo, hi); a[4] = fmaf(sc, lo, a[4]); a[5] = fmaf(sc, hi, a[5]);
  unpack2(w.w, lo, hi); a[6] = fmaf(sc, lo, a[6]); a[7] = fmaf(sc, hi, a[7]);
}

// ---------------- fp32 -> bf16 casts ----------------
__global__ void k_cast(const float* __restrict__ in, __hip_bfloat16* __restrict__ out,
                       int n4) {
  int i = blockIdx.x * 256 + threadIdx.x;
  if (i < n4) {
    float4 v = ((const float4*)in)[i];
    __hip_bfloat16 o[4] = {f2b(v.x), f2b(v.y), f2b(v.z), f2b(v.w)};
    ((short4*)out)[i] = *(short4*)o;
  }
}

__global__ void k_cast_w(const float* __restrict__ wq, const float* __restrict__ wk,
                         const float* __restrict__ wv, const float* __restrict__ wo,
                         const float* __restrict__ w1, const float* __restrict__ w2,
                         __hip_bfloat16* __restrict__ oq, __hip_bfloat16* __restrict__ ok,
                         __hip_bfloat16* __restrict__ ov, __hip_bfloat16* __restrict__ oo,
                         __hip_bfloat16* __restrict__ o1, __hip_bfloat16* __restrict__ o2) {
  int i = blockIdx.x * 256 + threadIdx.x;  // 131072 total
  if (i < 16384) oq[i] = f2b(wq[i]);
  else if (i < 32768) ok[i - 16384] = f2b(wk[i - 16384]);
  else if (i < 49152) ov[i - 32768] = f2b(wv[i - 32768]);
  else if (i < 65536) oo[i - 49152] = f2b(wo[i - 49152]);
  else if (i < 98304) o1[i - 65536] = f2b(w1[i - 65536]);
  else o2[i - 98304] = f2b(w2[i - 98304]);
}

// ---------------- CSR build via two-phase binning (bucket = dst>>8) ----------------
#define MAXB 512

__global__ void k_bhist(const int* __restrict__ dst, int* __restrict__ bh, int E) {
  __shared__ int cnt[MAXB];
  for (int i = threadIdx.x; i < MAXB; i += 256) cnt[i] = 0;
  __syncthreads();
  for (int e = blockIdx.x * 256 + threadIdx.x; e < E; e += gridDim.x * 256)
    atomicAdd(&cnt[dst[e] >> 8], 1);
  __syncthreads();
  for (int i = threadIdx.x; i < MAXB; i += 256)
    if (cnt[i]) atomicAdd(&bh[i], cnt[i]);
}

__global__ void k_bscan(const int* __restrict__ bh, int* __restrict__ bbase,
                        int* __restrict__ bcur, int B) {
  __shared__ int sd[MAXB];
  int t = threadIdx.x;
  int v = (t < B) ? bh[t] : 0;
  sd[t] = v;
  __syncthreads();
  for (int o = 1; o < MAXB; o <<= 1) {
    int x = (t >= o) ? sd[t - o] : 0;
    __syncthreads();
    sd[t] += x;
    __syncthreads();
  }
  if (t < B) {
    int e = sd[t] - v;
    bbase[t] = e;
    bcur[t] = e;
  }
}

// each block bins 4096 edges into contiguous per-bucket runs
__global__ __launch_bounds__(256) void k_bin(const int* __restrict__ src,
                                             const int* __restrict__ dst,
                                             int* __restrict__ bcur,
                                             uint2* __restrict__ binned, int E) {
  __shared__ int cnt[MAXB];
  __shared__ int base[MAXB];
  const int t = threadIdx.x;
  const int e0 = blockIdx.x * 4096;
  for (int i = t; i < MAXB; i += 256) cnt[i] = 0;
  __syncthreads();
  int myb[16], myr[16], ms[16], md[16];
#pragma unroll
  for (int j = 0; j < 16; ++j) {
    int e = e0 + j * 256 + t;
    if (e < E) {
      int d = dst[e];
      ms[j] = src[e];
      md[j] = d;
      int b = d >> 8;
      myb[j] = b;
      myr[j] = atomicAdd(&cnt[b], 1);
    } else {
      myb[j] = -1;
    }
  }
  __syncthreads();
  for (int i = t; i < MAXB; i += 256)
    base[i] = cnt[i] ? atomicAdd(&bcur[i], cnt[i]) : 0;
  __syncthreads();
#pragma unroll
  for (int j = 0; j < 16; ++j)
    if (myb[j] >= 0)
      binned[(size_t)base[myb[j]] + myr[j]] = make_uint2((unsigned)ms[j], (unsigned)md[j]);
}

// one block per bucket: per-node deg/offs + LDS-local fine scatter into csr
__global__ __launch_bounds__(256) void k_fine(const uint2* __restrict__ binned,
                                              const int* __restrict__ bh,
                                              const int* __restrict__ bbase,
                                              int* __restrict__ deg,
                                              int* __restrict__ offs,
                                              int* __restrict__ csr, int N) {
  __shared__ int cnt[256];
  __shared__ int cur[256];
  __shared__ int sd[256];
  const int b = blockIdx.x, t = threadIdx.x;
  const int node0 = b << 8;
  cnt[t] = 0;
  __syncthreads();
  const int s0 = bbase[b], len = bh[b];
  for (int i = t; i < len; i += 256) atomicAdd(&cnt[binned[(size_t)s0 + i].y & 255], 1);
  __syncthreads();
  int v = cnt[t];
  sd[t] = v;
  __syncthreads();
  for (int o = 1; o < 256; o <<= 1) {
    int x = (t >= o) ? sd[t - o] : 0;
    __syncthreads();
    sd[t] += x;
    __syncthreads();
  }
  int excl = sd[t] - v;
  cur[t] = excl;
  int node = node0 + t;
  if (node < N) {
    deg[node] = v;
    offs[node] = s0 + excl;
  }
  __syncthreads();
  for (int i = t; i < len; i += 256) {
    uint2 ed = binned[(size_t)s0 + i];
    int p = atomicAdd(&cur[ed.y & 255], 1);
    csr[s0 + p] = (int)ed.x;
  }
}

// ------- fused QKV GEMM (512 thr, full 128-wide): A read once, 8 waves share L1 ----
// KV layout: per node 8 heads x [K0..K15 | V0..V15] bf16 = 512 B rows.
__global__ __launch_bounds__(512) void gemm_qkv2(const short* __restrict__ A,
                                                 const short* __restrict__ Bq,
                                                 const short* __restrict__ Bk,
                                                 const short* __restrict__ Bv,
                                                 __hip_bfloat16* __restrict__ Q,
                                                 __hip_bfloat16* __restrict__ KV,
                                                 int Nrow) {
  const int t = threadIdx.x;
  const int lane = t & 63;
  const int ct = t >> 6;  // 0..7 (= head)
  const int n = lane & 15, quad = lane >> 4;
  short8 fq[4], fk[4], fv[4];
#pragma unroll
  for (int c = 0; c < 4; ++c) {
    short8 tq, tk, tv;
#pragma unroll
    for (int j = 0; j < 8; ++j) {
      int k = (c * 32 + quad * 8 + j) * 128 + ct * 16 + n;
      tq[j] = Bq[k]; tk[j] = Bk[k]; tv[j] = Bv[k];
    }
    fq[c] = tq; fk[c] = tk; fv[c] = tv;
  }
  int ntiles = Nrow >> 4;
  for (int rt = blockIdx.x; rt < ntiles; rt += gridDim.x) {
    float4v aq = {0.f, 0.f, 0.f, 0.f}, ak = aq, av = aq;
    const short* Ap = A + (size_t)(rt * 16 + n) * 128 + quad * 8;
#pragma unroll
    for (int c = 0; c < 4; ++c) {
      short8 a = *(const short8*)(Ap + c * 32);
      aq = mfma16(a, fq[c], aq);
      ak = mfma16(a, fk[c], ak);
      av = mfma16(a, fv[c], av);
    }
#pragma unroll
    for (int r = 0; r < 4; ++r) {
      int grow = rt * 16 + quad * 4 + r;
      Q[(size_t)grow * 128 + ct * 16 + n] = f2b(aq[r]);
      KV[(size_t)grow * 256 + ct * 32 + n] = f2b(ak[r]);
      KV[(size_t)grow * 256 + ct * 32 + 16 + n] = f2b(av[r]);
    }
  }
}

// ---- FFN1 GEMM (512 thr, full 256-wide: 8 waves x 2 col-tiles), bias+ReLU ----
__global__ __launch_bounds__(512) void gemm_ffn1(const short* __restrict__ A,
                                                 const short* __restrict__ B,
                                                 const float* __restrict__ bias,
                                                 __hip_bfloat16* __restrict__ Out,
                                                 int Nrow) {
  const int t = threadIdx.x;
  const int lane = t & 63;
  const int wv = t >> 6;  // 0..7
  const int n = lane & 15, quad = lane >> 4;
  short8 bfr[2][4];
  float biasv[2];
#pragma unroll
  for (int c2 = 0; c2 < 2; ++c2) {
    int col = (wv * 2 + c2) * 16 + n;
#pragma unroll
    for (int c = 0; c < 4; ++c) {
      short8 tmp;
#pragma unroll
      for (int j = 0; j < 8; ++j)
        tmp[j] = B[(size_t)(c * 32 + quad * 8 + j) * 256 + col];
      bfr[c2][c] = tmp;
    }
    biasv[c2] = bias[col];
  }
  int ntiles = Nrow >> 4;
  for (int rt = blockIdx.x; rt < ntiles; rt += gridDim.x) {
    float4v acc[2];
    acc[0] = (float4v){0.f, 0.f, 0.f, 0.f};
    acc[1] = acc[0];
    const short* Ap = A + (size_t)(rt * 16 + n) * 128 + quad * 8;
#pragma unroll
    for (int c = 0; c < 4; ++c) {
      short8 a = *(const short8*)(Ap + c * 32);
      acc[0] = mfma16(a, bfr[0][c], acc[0]);
      acc[1] = mfma16(a, bfr[1][c], acc[1]);
    }
#pragma unroll
    for (int c2 = 0; c2 < 2; ++c2)
#pragma unroll
      for (int r = 0; r < 4; ++r) {
        int grow = rt * 16 + quad * 4 + r;
        float v = fmaxf(acc[c2][r] + biasv[c2], 0.f);
        Out[(size_t)grow * 256 + (wv * 2 + c2) * 16 + n] = f2b(v);
      }
  }
}

// ------ GEMM + bias + residual + LayerNorm (M=128 fixed), fp32/bf16 generic ------
template <int K, typename TR, typename TO>
__global__ __launch_bounds__(512) void ln_gemm(const short* __restrict__ A,
                                               const short* __restrict__ B,
                                               const float* __restrict__ bias,
                                               const TR* __restrict__ resid,
                                               const float* __restrict__ gam,
                                               const float* __restrict__ bet,
                                               TO* __restrict__ Out, int Nrow) {
  __shared__ float tile[16][132];
  const int t = threadIdx.x;
  const int lane = t & 63;
  const int ct = t >> 6;  // wave id = col tile (8 waves x 16 cols = 128)
  const int n = lane & 15, quad = lane >> 4;
  short8 bfr[K / 32];
#pragma unroll
  for (int c = 0; c < K / 32; ++c) {
    short8 tmp;
#pragma unroll
    for (int j = 0; j < 8; ++j)
      tmp[j] = B[(size_t)(c * 32 + quad * 8 + j) * 128 + ct * 16 + n];
    bfr[c] = tmp;
  }
  float biasv = bias[ct * 16 + n];
  const int row2 = t >> 5, sub = t & 31;
  float ga0 = gam[sub],      ga1 = gam[sub + 32];
  float ga2 = gam[sub + 64], ga3 = gam[sub + 96];
  float be0 = bet[sub],      be1 = bet[sub + 32];
  float be2 = bet[sub + 64], be3 = bet[sub + 96];
  int ntiles = Nrow >> 4;
  for (int rt = blockIdx.x; rt < ntiles; rt += gridDim.x) {
    float4v acc = {0.f, 0.f, 0.f, 0.f};
    const short* Ap = A + (size_t)(rt * 16 + n) * K + quad * 8;
#pragma unroll
    for (int c = 0; c < K / 32; ++c)
      acc = mfma16(*(const short8*)(Ap + c * 32), bfr[c], acc);
#pragma unroll
    for (int r = 0; r < 4; ++r) {
      int rr = quad * 4 + r;
      size_t g = (size_t)(rt * 16 + rr) * 128 + ct * 16 + n;
      tile[rr][ct * 16 + n] = acc[r] + biasv + ldf(resid, g);
    }
    __syncthreads();
    float x0 = tile[row2][sub], x1 = tile[row2][sub + 32];
    float x2 = tile[row2][sub + 64], x3 = tile[row2][sub + 96];
    float s = x0 + x1 + x2 + x3;
    float s2 = x0 * x0 + x1 * x1 + x2 * x2 + x3 * x3;
#pragma unroll
    for (int o = 16; o >= 1; o >>= 1) {
      s += __shfl_xor(s, o);
      s2 += __shfl_xor(s2, o);
    }
    float mean = s * 0.0078125f;
    float var = s2 * 0.0078125f - mean * mean;
    float rstd = rsqrtf(var + 1e-5f);
    size_t base = (size_t)(rt * 16 + row2) * 128;
    stf(Out, base + sub,      (x0 - mean) * rstd * ga0 + be0);
    stf(Out, base + sub + 32, (x1 - mean) * rstd * ga1 + be1);
    stf(Out, base + sub + 64, (x2 - mean) * rstd * ga2 + be2);
    stf(Out, base + sub + 96, (x3 - mean) * rstd * ga3 + be3);
    __syncthreads();
  }
}

// ---------------- attention aggregation v3: in-lane dot, lane = (edge8, head) ------
// One wave per node. Lane (e8,hd) processes edge i+e8 for head hd; K.Q dot fully
// in-lane (no cross-lane in the loop). One 3-round shuffle reduce per node.
__global__ __launch_bounds__(64) void attn_agg3(const uint4* __restrict__ Q4,
                                                const uint4* __restrict__ KV4,
                                                const int* __restrict__ offs,
                                                const int* __restrict__ deg,
                                                const int* __restrict__ csr,
                                                uint4* __restrict__ AT4) {
  const int node = blockIdx.x;
  const int t = threadIdx.x;
  const int e8 = t >> 3, hd = t & 7;
  uint4 qa = Q4[(size_t)node * 16 + hd * 2];
  uint4 qb = Q4[(size_t)node * 16 + hd * 2 + 1];
  float q[16];
  unp8(qa, q);
  unp8(qb, q + 8);
  float acc[16];
#pragma unroll
  for (int d = 0; d < 16; ++d) acc[d] = 0.f;
  float z = 0.f;
  const int st = offs[node], dg = deg[node];
  for (int i = 0; i < dg; i += 8) {
    int idx = i + e8;
    bool valid = idx < dg;
    int s = csr[st + (valid ? idx : i)];
    const uint4* kv = KV4 + (size_t)s * 32 + hd * 4;
    uint4 ka = kv[0];
    uint4 kb = kv[1];
    uint4 va = kv[2];
    uint4 vb = kv[3];
    float p = dot8(ka, q) + dot8(kb, q + 8);
    float sc = __expf(fminf(fmaxf(p * 0.25f, -5.f), 5.f));
    sc = valid ? sc : 0.f;
    z += sc;
    fma8(va, sc, acc);
    fma8(vb, sc, acc + 8);
  }
#pragma unroll
  for (int m = 8; m <= 32; m <<= 1) {
    z += __shfl_xor(z, m);
#pragma unroll
    for (int d = 0; d < 16; ++d) acc[d] += __shfl_xor(acc[d], m);
  }
  if (e8 == 0) {
    float inv = (z > 0.f) ? 1.f / z : 1.f;
    unsigned r[8];
#pragma unroll
    for (int j = 0; j < 8; ++j)
      r[j] = (unsigned)f2b_bits(acc[2 * j] * inv) |
             ((unsigned)f2b_bits(acc[2 * j + 1] * inv) << 16);
    AT4[(size_t)node * 16 + hd * 2] = make_uint4(r[0], r[1], r[2], r[3]);
    AT4[(size_t)node * 16 + hd * 2 + 1] = make_uint4(r[4], r[5], r[6], r[7]);
  }
}

// ---------------- launch ----------------
extern "C" void kernel_launch(void* const* d_in, const int* in_sizes, int n_in,
                              void* d_out, int out_size, void* d_ws, size_t ws_size,
                              hipStream_t stream) {
  const float* h = (const float*)d_in[0];
  const int* src = (const int*)d_in[1];
  const int* dst = (const int*)d_in[2];
  const float* Wq = (const float*)d_in[3];
  const float* Wk = (const float*)d_in[4];
  const float* Wv = (const float*)d_in[5];
  const float* Wo = (const float*)d_in[6];
  const float* bo = (const float*)d_in[7];
  const float* g1 = (const float*)d_in[8];
  const float* b1 = (const float*)d_in[9];
  const float* g2 = (const float*)d_in[10];
  const float* b2 = (const float*)d_in[11];
  const float* W1 = (const float*)d_in[12];
  const float* c1 = (const float*)d_in[13];
  const float* W2 = (const float*)d_in[14];
  const float* c2 = (const float*)d_in[15];

  const int N = in_sizes[0] / D;
  const int E = in_sizes[1];
  const int B = (N + 255) >> 8;

  char* p = (char*)d_ws;
  auto carve = [&](size_t bytes) {
    char* r = p;
    p += (bytes + 255) & ~(size_t)255;
    return r;
  };
  short* hb = (short*)carve((size_t)N * D * 2);        // bf16 h; later AT
  short* Qb = (short*)carve((size_t)N * D * 2);        // later hh
  short* KVb = (short*)carve((size_t)N * D * 4);       // head-blocked K|V; later tmid
  short* wq = (short*)carve(16384 * 2);
  short* wk = (short*)carve(16384 * 2);
  short* wv = (short*)carve(16384 * 2);
  short* wo = (short*)carve(16384 * 2);
  short* w1 = (short*)carve(32768 * 2);
  short* w2 = (short*)carve(32768 * 2);
  int* deg = (int*)carve((size_t)N * 4);
  int* offs = (int*)carve((size_t)N * 4);
  int* bh = (int*)carve(MAXB * 4);
  int* bbase = (int*)carve(MAXB * 4);
  int* bcur = (int*)carve(MAXB * 4);
  uint2* binned = (uint2*)carve((size_t)E * 8);
  int* csr = (int*)carve((size_t)E * 4);
  short* ATb = hb;           // alias: h-bf16 dead after qkv gemm
  short* hh = Qb;            // alias: Q dead after attn_agg
  short* tmid = KVb;         // alias: N*256 bf16; K/V dead after attn_agg

  hipMemsetAsync(bh, 0, MAXB * 4, stream);
  k_bhist<<<1024, 256, 0, stream>>>(dst, bh, E);
  k_bscan<<<1, MAXB, 0, stream>>>(bh, bbase, bcur, B);
  k_bin<<<(E + 4095) / 4096, 256, 0, stream>>>(src, dst, bcur, binned, E);
  k_fine<<<B, 256, 0, stream>>>(binned, bh, bbase, deg, offs, csr, N);

  int n4 = N * D / 4;
  k_cast<<<(n4 + 255) / 256, 256, 0, stream>>>(h, (__hip_bfloat16*)hb, n4);
  k_cast_w<<<512, 256, 0, stream>>>(Wq, Wk, Wv, Wo, W1, W2,
                                    (__hip_bfloat16*)wq, (__hip_bfloat16*)wk,
                                    (__hip_bfloat16*)wv, (__hip_bfloat16*)wo,
                                    (__hip_bfloat16*)w1, (__hip_bfloat16*)w2);

  gemm_qkv2<<<1024, 512, 0, stream>>>(hb, wq, wk, wv, (__hip_bfloat16*)Qb,
                                      (__hip_bfloat16*)KVb, N);

  attn_agg3<<<N, 64, 0, stream>>>((const uint4*)Qb, (const uint4*)KVb,
                                  offs, deg, csr, (uint4*)ATb);

  ln_gemm<128, float, __hip_bfloat16><<<1024, 512, 0, stream>>>(
      ATb, wo, bo, h, g1, b1, (__hip_bfloat16*)hh, N);
  gemm_ffn1<<<1024, 512, 0, stream>>>(hh, w1, c1, (__hip_bfloat16*)tmid, N);
  ln_gemm<256, __hip_bfloat16, float><<<1024, 512, 0, stream>>>(
      tmid, w2, c2, (const __hip_bfloat16*)hh, g2, b2, (float*)d_out, N);
}

// Round 6
// 468.855 us; speedup vs baseline: 1.6859x; 1.0087x over previous
//
#include <hip/hip_runtime.h>
#include <hip/hip_bf16.h>

#define D 128

typedef __attribute__((ext_vector_type(8))) short short8;
typedef __attribute__((ext_vector_type(4))) float float4v;

__device__ __forceinline__ float4v mfma16(short8 a, short8 b, float4v c) {
  return __builtin_amdgcn_mfma_f32_16x16x32_bf16(a, b, c, 0, 0, 0);
}
__device__ __forceinline__ float b2f(__hip_bfloat16 x) { return __bfloat162float(x); }
__device__ __forceinline__ __hip_bfloat16 f2b(float x) { return __float2bfloat16(x); }
__device__ __forceinline__ unsigned short f2b_bits(float x) {
  __hip_bfloat16 h = __float2bfloat16(x);
  return *reinterpret_cast<unsigned short*>(&h);
}

__device__ __forceinline__ float ldf(const float* p, size_t i) { return p[i]; }
__device__ __forceinline__ float ldf(const __hip_bfloat16* p, size_t i) { return b2f(p[i]); }
__device__ __forceinline__ void stf(float* p, size_t i, float v) { p[i] = v; }
__device__ __forceinline__ void stf(__hip_bfloat16* p, size_t i, float v) { p[i] = f2b(v); }

__device__ __forceinline__ void unpack2(unsigned w, float& lo, float& hi) {
  lo = __uint_as_float(w << 16);
  hi = __uint_as_float(w & 0xffff0000u);
}
__device__ __forceinline__ void unp8(uint4 w, float* q) {
  unpack2(w.x, q[0], q[1]);
  unpack2(w.y, q[2], q[3]);
  unpack2(w.z, q[4], q[5]);
  unpack2(w.w, q[6], q[7]);
}
__device__ __forceinline__ float dot8(uint4 w, const float* q) {
  float p = 0.f, lo, hi;
  unpack2(w.x, lo, hi); p = fmaf(q[0], lo, p); p = fmaf(q[1], hi, p);
  unpack2(w.y, lo, hi); p = fmaf(q[2], lo, p); p = fmaf(q[3], hi, p);
  unpack2(w.z, lo, hi); p = fmaf(q[4], lo, p); p = fmaf(q[5], hi, p);
  unpack2(w.w, lo, hi); p = fmaf(q[6], lo, p); p = fmaf(q[7], hi, p);
  return p;
}
__device__ __forceinline__ void fma8(uint4 w, float sc, float* a) {
  float lo, hi;
  unpack2(w.x, lo, hi); a[0] = fmaf(sc, lo, a[0]); a[1] = fmaf(sc, hi, a[1]);
  unpack2(w.y, lo, hi); a[2] = fmaf(sc, lo, a[2]); a[3] = fmaf(sc, hi, a[3]);
  unpack2(w.z, lo, hi); a[4] = fmaf(sc, lo, a[4]); a[5] = fmaf(sc, hi, a[5]);
  unpack2(w.w, lo, hi); a[6] = fmaf(sc, lo, a[6]); a[7] = fmaf(sc, hi, a[7]);
}

// ---------------- weight casts (tiny) ----------------
__global__ void k_cast_w(const float* __restrict__ wq, const float* __restrict__ wk,
                         const float* __restrict__ wv, const float* __restrict__ wo,
                         const float* __restrict__ w1, const float* __restrict__ w2,
                         __hip_bfloat16* __restrict__ oq, __hip_bfloat16* __restrict__ ok,
                         __hip_bfloat16* __restrict__ ov, __hip_bfloat16* __restrict__ oo,
                         __hip_bfloat16* __restrict__ o1, __hip_bfloat16* __restrict__ o2) {
  int i = blockIdx.x * 256 + threadIdx.x;  // 131072 total
  if (i < 16384) oq[i] = f2b(wq[i]);
  else if (i < 32768) ok[i - 16384] = f2b(wk[i - 16384]);
  else if (i < 49152) ov[i - 32768] = f2b(wv[i - 32768]);
  else if (i < 65536) oo[i - 49152] = f2b(wo[i - 49152]);
  else if (i < 98304) o1[i - 65536] = f2b(w1[i - 65536]);
  else o2[i - 98304] = f2b(w2[i - 98304]);
}

// ---------------- CSR build via two-phase binning (bucket = dst>>8) ----------------
#define MAXB 512

__global__ void k_bhist(const int* __restrict__ dst, int* __restrict__ bh, int E) {
  __shared__ int cnt[MAXB];
  for (int i = threadIdx.x; i < MAXB; i += 256) cnt[i] = 0;
  __syncthreads();
  for (int e = blockIdx.x * 256 + threadIdx.x; e < E; e += gridDim.x * 256)
    atomicAdd(&cnt[dst[e] >> 8], 1);
  __syncthreads();
  for (int i = threadIdx.x; i < MAXB; i += 256)
    if (cnt[i]) atomicAdd(&bh[i], cnt[i]);
}

__global__ void k_bscan(const int* __restrict__ bh, int* __restrict__ bbase,
                        int* __restrict__ bcur, int B) {
  __shared__ int sd[MAXB];
  int t = threadIdx.x;
  int v = (t < B) ? bh[t] : 0;
  sd[t] = v;
  __syncthreads();
  for (int o = 1; o < MAXB; o <<= 1) {
    int x = (t >= o) ? sd[t - o] : 0;
    __syncthreads();
    sd[t] += x;
    __syncthreads();
  }
  if (t < B) {
    int e = sd[t] - v;
    bbase[t] = e;
    bcur[t] = e;
  }
}

// each block bins 4096 edges into contiguous per-bucket runs
__global__ __launch_bounds__(256) void k_bin(const int* __restrict__ src,
                                             const int* __restrict__ dst,
                                             int* __restrict__ bcur,
                                             uint2* __restrict__ binned, int E) {
  __shared__ int cnt[MAXB];
  __shared__ int base[MAXB];
  const int t = threadIdx.x;
  const int e0 = blockIdx.x * 4096;
  for (int i = t; i < MAXB; i += 256) cnt[i] = 0;
  __syncthreads();
  int myb[16], myr[16], ms[16], md[16];
#pragma unroll
  for (int j = 0; j < 16; ++j) {
    int e = e0 + j * 256 + t;
    if (e < E) {
      int d = dst[e];
      ms[j] = src[e];
      md[j] = d;
      int b = d >> 8;
      myb[j] = b;
      myr[j] = atomicAdd(&cnt[b], 1);
    } else {
      myb[j] = -1;
    }
  }
  __syncthreads();
  for (int i = t; i < MAXB; i += 256)
    base[i] = cnt[i] ? atomicAdd(&bcur[i], cnt[i]) : 0;
  __syncthreads();
#pragma unroll
  for (int j = 0; j < 16; ++j)
    if (myb[j] >= 0)
      binned[(size_t)base[myb[j]] + myr[j]] = make_uint2((unsigned)ms[j], (unsigned)md[j]);
}

// one block per bucket: per-node deg/offs + LDS-local fine scatter into csr
__global__ __launch_bounds__(256) void k_fine(const uint2* __restrict__ binned,
                                              const int* __restrict__ bh,
                                              const int* __restrict__ bbase,
                                              int* __restrict__ deg,
                                              int* __restrict__ offs,
                                              int* __restrict__ csr, int N) {
  __shared__ int cnt[256];
  __shared__ int cur[256];
  __shared__ int sd[256];
  const int b = blockIdx.x, t = threadIdx.x;
  const int node0 = b << 8;
  cnt[t] = 0;
  __syncthreads();
  const int s0 = bbase[b], len = bh[b];
  for (int i = t; i < len; i += 256) atomicAdd(&cnt[binned[(size_t)s0 + i].y & 255], 1);
  __syncthreads();
  int v = cnt[t];
  sd[t] = v;
  __syncthreads();
  for (int o = 1; o < 256; o <<= 1) {
    int x = (t >= o) ? sd[t - o] : 0;
    __syncthreads();
    sd[t] += x;
    __syncthreads();
  }
  int excl = sd[t] - v;
  cur[t] = excl;
  int node = node0 + t;
  if (node < N) {
    deg[node] = v;
    offs[node] = s0 + excl;
  }
  __syncthreads();
  for (int i = t; i < len; i += 256) {
    uint2 ed = binned[(size_t)s0 + i];
    int p = atomicAdd(&cur[ed.y & 255], 1);
    csr[s0 + p] = (int)ed.x;
  }
}

// ------- fused QKV GEMM: reads h fp32, converts in-register (k_cast deleted) -------
// KV layout: per node 8 heads x [K0..K15 | V0..V15] bf16 = 512 B rows.
__global__ __launch_bounds__(512) void gemm_qkv2(const float* __restrict__ A,
                                                 const short* __restrict__ Bq,
                                                 const short* __restrict__ Bk,
                                                 const short* __restrict__ Bv,
                                                 __hip_bfloat16* __restrict__ Q,
                                                 __hip_bfloat16* __restrict__ KV,
                                                 int Nrow) {
  const int t = threadIdx.x;
  const int lane = t & 63;
  const int ct = t >> 6;  // 0..7 (= head)
  const int n = lane & 15, quad = lane >> 4;
  short8 fq[4], fk[4], fv[4];
#pragma unroll
  for (int c = 0; c < 4; ++c) {
    short8 tq, tk, tv;
#pragma unroll
    for (int j = 0; j < 8; ++j) {
      int k = (c * 32 + quad * 8 + j) * 128 + ct * 16 + n;
      tq[j] = Bq[k]; tk[j] = Bk[k]; tv[j] = Bv[k];
    }
    fq[c] = tq; fk[c] = tk; fv[c] = tv;
  }
  int ntiles = Nrow >> 4;
  for (int rt = blockIdx.x; rt < ntiles; rt += gridDim.x) {
    float4v aq = {0.f, 0.f, 0.f, 0.f}, ak = aq, av = aq;
    const float* Ap = A + (size_t)(rt * 16 + n) * 128 + quad * 8;
#pragma unroll
    for (int c = 0; c < 4; ++c) {
      float4 u0 = *(const float4*)(Ap + c * 32);
      float4 u1 = *(const float4*)(Ap + c * 32 + 4);
      short8 a;
      a[0] = (short)f2b_bits(u0.x); a[1] = (short)f2b_bits(u0.y);
      a[2] = (short)f2b_bits(u0.z); a[3] = (short)f2b_bits(u0.w);
      a[4] = (short)f2b_bits(u1.x); a[5] = (short)f2b_bits(u1.y);
      a[6] = (short)f2b_bits(u1.z); a[7] = (short)f2b_bits(u1.w);
      aq = mfma16(a, fq[c], aq);
      ak = mfma16(a, fk[c], ak);
      av = mfma16(a, fv[c], av);
    }
#pragma unroll
    for (int r = 0; r < 4; ++r) {
      int grow = rt * 16 + quad * 4 + r;
      Q[(size_t)grow * 128 + ct * 16 + n] = f2b(aq[r]);
      KV[(size_t)grow * 256 + ct * 32 + n] = f2b(ak[r]);
      KV[(size_t)grow * 256 + ct * 32 + 16 + n] = f2b(av[r]);
    }
  }
}

// ------ GEMM + bias + residual + LayerNorm (M=128), ping-pong LDS, 1 barrier/iter ---
template <int K, typename TR, typename TO>
__global__ __launch_bounds__(512) void ln_gemm(const short* __restrict__ A,
                                               const short* __restrict__ B,
                                               const float* __restrict__ bias,
                                               const TR* __restrict__ resid,
                                               const float* __restrict__ gam,
                                               const float* __restrict__ bet,
                                               TO* __restrict__ Out, int Nrow) {
  __shared__ float tile[2][16][132];
  const int t = threadIdx.x;
  const int lane = t & 63;
  const int ct = t >> 6;  // wave id = col tile (8 waves x 16 cols = 128)
  const int n = lane & 15, quad = lane >> 4;
  short8 bfr[K / 32];
#pragma unroll
  for (int c = 0; c < K / 32; ++c) {
    short8 tmp;
#pragma unroll
    for (int j = 0; j < 8; ++j)
      tmp[j] = B[(size_t)(c * 32 + quad * 8 + j) * 128 + ct * 16 + n];
    bfr[c] = tmp;
  }
  float biasv = bias[ct * 16 + n];
  const int row2 = t >> 5, sub = t & 31;
  float ga0 = gam[sub],      ga1 = gam[sub + 32];
  float ga2 = gam[sub + 64], ga3 = gam[sub + 96];
  float be0 = bet[sub],      be1 = bet[sub + 32];
  float be2 = bet[sub + 64], be3 = bet[sub + 96];
  int ntiles = Nrow >> 4;
  int pp = 0;
  for (int rt = blockIdx.x; rt < ntiles; rt += gridDim.x, pp ^= 1) {
    float4v acc = {0.f, 0.f, 0.f, 0.f};
    const short* Ap = A + (size_t)(rt * 16 + n) * K + quad * 8;
#pragma unroll
    for (int c = 0; c < K / 32; ++c)
      acc = mfma16(*(const short8*)(Ap + c * 32), bfr[c], acc);
#pragma unroll
    for (int r = 0; r < 4; ++r) {
      int rr = quad * 4 + r;
      size_t g = (size_t)(rt * 16 + rr) * 128 + ct * 16 + n;
      tile[pp][rr][ct * 16 + n] = acc[r] + biasv + ldf(resid, g);
    }
    __syncthreads();
    float x0 = tile[pp][row2][sub], x1 = tile[pp][row2][sub + 32];
    float x2 = tile[pp][row2][sub + 64], x3 = tile[pp][row2][sub + 96];
    float s = x0 + x1 + x2 + x3;
    float s2 = x0 * x0 + x1 * x1 + x2 * x2 + x3 * x3;
#pragma unroll
    for (int o = 16; o >= 1; o >>= 1) {
      s += __shfl_xor(s, o);
      s2 += __shfl_xor(s2, o);
    }
    float mean = s * 0.0078125f;
    float var = s2 * 0.0078125f - mean * mean;
    float rstd = rsqrtf(var + 1e-5f);
    size_t base = (size_t)(rt * 16 + row2) * 128;
    stf(Out, base + sub,      (x0 - mean) * rstd * ga0 + be0);
    stf(Out, base + sub + 32, (x1 - mean) * rstd * ga1 + be1);
    stf(Out, base + sub + 64, (x2 - mean) * rstd * ga2 + be2);
    stf(Out, base + sub + 96, (x3 - mean) * rstd * ga3 + be3);
  }
}

// ------ fused FFN: out = LN(hh + relu(hh@W1+c1)@W2 + c2); mid tile in LDS ------
__global__ __launch_bounds__(512) void ffn_ln(const short* __restrict__ hh,
                                              const short* __restrict__ W1b,
                                              const float* __restrict__ c1,
                                              const short* __restrict__ W2b,
                                              const float* __restrict__ c2,
                                              const float* __restrict__ gam,
                                              const float* __restrict__ bet,
                                              float* __restrict__ Out, int Nrow) {
  __shared__ short mid[16][264];   // 256 + 8 pad (b128-clean, conflict-light)
  __shared__ float tile[16][132];
  const int t = threadIdx.x;
  const int lane = t & 63;
  const int wv = t >> 6;  // 0..7
  const int n = lane & 15, quad = lane >> 4;
  // W1 fragments: 2 col-tiles (cols wv*32..+32), K=128
  short8 f1[2][4];
  float b1v[2];
#pragma unroll
  for (int cc = 0; cc < 2; ++cc) {
    int col = (wv * 2 + cc) * 16 + n;
#pragma unroll
    for (int c = 0; c < 4; ++c) {
      short8 tmp;
#pragma unroll
      for (int j = 0; j < 8; ++j)
        tmp[j] = W1b[(size_t)(c * 32 + quad * 8 + j) * 256 + col];
      f1[cc][c] = tmp;
    }
    b1v[cc] = c1[col];
  }
  // W2 fragments: 1 col-tile (cols wv*16+n), K=256
  short8 f2[8];
#pragma unroll
  for (int c = 0; c < 8; ++c) {
    short8 tmp;
#pragma unroll
    for (int j = 0; j < 8; ++j)
      tmp[j] = W2b[(size_t)(c * 32 + quad * 8 + j) * 128 + wv * 16 + n];
    f2[c] = tmp;
  }
  float b2v = c2[wv * 16 + n];
  const int row2 = t >> 5, sub = t & 31;
  float ga0 = gam[sub],      ga1 = gam[sub + 32];
  float ga2 = gam[sub + 64], ga3 = gam[sub + 96];
  float be0 = bet[sub],      be1 = bet[sub + 32];
  float be2 = bet[sub + 64], be3 = bet[sub + 96];
  int ntiles = Nrow >> 4;
  for (int rt = blockIdx.x; rt < ntiles; rt += gridDim.x) {
    // GEMM1: mid = relu(hh @ W1 + c1), 16 x 256 tile -> LDS (bf16)
    float4v a1[2];
    a1[0] = (float4v){0.f, 0.f, 0.f, 0.f};
    a1[1] = a1[0];
    const short* Ap = hh + (size_t)(rt * 16 + n) * 128 + quad * 8;
#pragma unroll
    for (int c = 0; c < 4; ++c) {
      short8 a = *(const short8*)(Ap + c * 32);
      a1[0] = mfma16(a, f1[0][c], a1[0]);
      a1[1] = mfma16(a, f1[1][c], a1[1]);
    }
#pragma unroll
    for (int cc = 0; cc < 2; ++cc)
#pragma unroll
      for (int r = 0; r < 4; ++r)
        mid[quad * 4 + r][(wv * 2 + cc) * 16 + n] =
            (short)f2b_bits(fmaxf(a1[cc][r] + b1v[cc], 0.f));
    __syncthreads();
    // GEMM2: acc = mid @ W2 over K=256, A-fragments from LDS
    float4v acc = {0.f, 0.f, 0.f, 0.f};
#pragma unroll
    for (int c = 0; c < 8; ++c) {
      short8 a = *(const short8*)&mid[n][quad * 8 + c * 32];
      acc = mfma16(a, f2[c], acc);
    }
#pragma unroll
    for (int r = 0; r < 4; ++r) {
      int rr = quad * 4 + r;
      size_t g = (size_t)(rt * 16 + rr) * 128 + wv * 16 + n;
      tile[rr][wv * 16 + n] = acc[r] + b2v + b2f(((const __hip_bfloat16*)hh)[g]);
    }
    __syncthreads();
    float x0 = tile[row2][sub], x1 = tile[row2][sub + 32];
    float x2 = tile[row2][sub + 64], x3 = tile[row2][sub + 96];
    float s = x0 + x1 + x2 + x3;
    float s2 = x0 * x0 + x1 * x1 + x2 * x2 + x3 * x3;
#pragma unroll
    for (int o = 16; o >= 1; o >>= 1) {
      s += __shfl_xor(s, o);
      s2 += __shfl_xor(s2, o);
    }
    float mean = s * 0.0078125f;
    float var = s2 * 0.0078125f - mean * mean;
    float rstd = rsqrtf(var + 1e-5f);
    size_t base = (size_t)(rt * 16 + row2) * 128;
    Out[base + sub]      = (x0 - mean) * rstd * ga0 + be0;
    Out[base + sub + 32] = (x1 - mean) * rstd * ga1 + be1;
    Out[base + sub + 64] = (x2 - mean) * rstd * ga2 + be2;
    Out[base + sub + 96] = (x3 - mean) * rstd * ga3 + be3;
  }
}

// ---------------- attention aggregation v3: in-lane dot, lane = (edge8, head) ------
__global__ __launch_bounds__(64) void attn_agg3(const uint4* __restrict__ Q4,
                                                const uint4* __restrict__ KV4,
                                                const int* __restrict__ offs,
                                                const int* __restrict__ deg,
                                                const int* __restrict__ csr,
                                                uint4* __restrict__ AT4) {
  const int node = blockIdx.x;
  const int t = threadIdx.x;
  const int e8 = t >> 3, hd = t & 7;
  uint4 qa = Q4[(size_t)node * 16 + hd * 2];
  uint4 qb = Q4[(size_t)node * 16 + hd * 2 + 1];
  float q[16];
  unp8(qa, q);
  unp8(qb, q + 8);
  float acc[16];
#pragma unroll
  for (int d = 0; d < 16; ++d) acc[d] = 0.f;
  float z = 0.f;
  const int st = offs[node], dg = deg[node];
  for (int i = 0; i < dg; i += 8) {
    int idx = i + e8;
    bool valid = idx < dg;
    int s = csr[st + (valid ? idx : i)];
    const uint4* kv = KV4 + (size_t)s * 32 + hd * 4;
    uint4 ka = kv[0];
    uint4 kb = kv[1];
    uint4 va = kv[2];
    uint4 vb = kv[3];
    float p = dot8(ka, q) + dot8(kb, q + 8);
    float sc = __expf(fminf(fmaxf(p * 0.25f, -5.f), 5.f));
    sc = valid ? sc : 0.f;
    z += sc;
    fma8(va, sc, acc);
    fma8(vb, sc, acc + 8);
  }
#pragma unroll
  for (int m = 8; m <= 32; m <<= 1) {
    z += __shfl_xor(z, m);
#pragma unroll
    for (int d = 0; d < 16; ++d) acc[d] += __shfl_xor(acc[d], m);
  }
  if (e8 == 0) {
    float inv = (z > 0.f) ? 1.f / z : 1.f;
    unsigned r[8];
#pragma unroll
    for (int j = 0; j < 8; ++j)
      r[j] = (unsigned)f2b_bits(acc[2 * j] * inv) |
             ((unsigned)f2b_bits(acc[2 * j + 1] * inv) << 16);
    AT4[(size_t)node * 16 + hd * 2] = make_uint4(r[0], r[1], r[2], r[3]);
    AT4[(size_t)node * 16 + hd * 2 + 1] = make_uint4(r[4], r[5], r[6], r[7]);
  }
}

// ---------------- launch ----------------
extern "C" void kernel_launch(void* const* d_in, const int* in_sizes, int n_in,
                              void* d_out, int out_size, void* d_ws, size_t ws_size,
                              hipStream_t stream) {
  const float* h = (const float*)d_in[0];
  const int* src = (const int*)d_in[1];
  const int* dst = (const int*)d_in[2];
  const float* Wq = (const float*)d_in[3];
  const float* Wk = (const float*)d_in[4];
  const float* Wv = (const float*)d_in[5];
  const float* Wo = (const float*)d_in[6];
  const float* bo = (const float*)d_in[7];
  const float* g1 = (const float*)d_in[8];
  const float* b1 = (const float*)d_in[9];
  const float* g2 = (const float*)d_in[10];
  const float* b2 = (const float*)d_in[11];
  const float* W1 = (const float*)d_in[12];
  const float* c1 = (const float*)d_in[13];
  const float* W2 = (const float*)d_in[14];
  const float* c2 = (const float*)d_in[15];

  const int N = in_sizes[0] / D;
  const int E = in_sizes[1];
  const int B = (N + 255) >> 8;

  char* p = (char*)d_ws;
  auto carve = [&](size_t bytes) {
    char* r = p;
    p += (bytes + 255) & ~(size_t)255;
    return r;
  };
  short* ATb = (short*)carve((size_t)N * D * 2);
  short* Qb = (short*)carve((size_t)N * D * 2);        // later hh
  short* KVb = (short*)carve((size_t)N * D * 4);       // head-blocked K|V
  short* wq = (short*)carve(16384 * 2);
  short* wk = (short*)carve(16384 * 2);
  short* wv = (short*)carve(16384 * 2);
  short* wo = (short*)carve(16384 * 2);
  short* w1 = (short*)carve(32768 * 2);
  short* w2 = (short*)carve(32768 * 2);
  int* deg = (int*)carve((size_t)N * 4);
  int* offs = (int*)carve((size_t)N * 4);
  int* bh = (int*)carve(MAXB * 4);
  int* bbase = (int*)carve(MAXB * 4);
  int* bcur = (int*)carve(MAXB * 4);
  uint2* binned = (uint2*)carve((size_t)E * 8);
  int* csr = (int*)carve((size_t)E * 4);
  short* hh = Qb;  // alias: Q dead after attn_agg

  hipMemsetAsync(bh, 0, MAXB * 4, stream);
  k_bhist<<<1024, 256, 0, stream>>>(dst, bh, E);
  k_bscan<<<1, MAXB, 0, stream>>>(bh, bbase, bcur, B);
  k_bin<<<(E + 4095) / 4096, 256, 0, stream>>>(src, dst, bcur, binned, E);
  k_fine<<<B, 256, 0, stream>>>(binned, bh, bbase, deg, offs, csr, N);

  k_cast_w<<<512, 256, 0, stream>>>(Wq, Wk, Wv, Wo, W1, W2,
                                    (__hip_bfloat16*)wq, (__hip_bfloat16*)wk,
                                    (__hip_bfloat16*)wv, (__hip_bfloat16*)wo,
                                    (__hip_bfloat16*)w1, (__hip_bfloat16*)w2);

  gemm_qkv2<<<1536, 512, 0, stream>>>(h, wq, wk, wv, (__hip_bfloat16*)Qb,
                                      (__hip_bfloat16*)KVb, N);

  attn_agg3<<<N, 64, 0, stream>>>((const uint4*)Qb, (const uint4*)KVb,
                                  offs, deg, csr, (uint4*)ATb);

  ln_gemm<128, float, __hip_bfloat16><<<1536, 512, 0, stream>>>(
      ATb, wo, bo, h, g1, b1, (__hip_bfloat16*)hh, N);
  ffn_ln<<<1536, 512, 0, stream>>>(hh, w1, c1, w2, c2, g2, b2, (float*)d_out, N);
}